// Round 22
// baseline (180.737 us; speedup 1.0000x reference)
//
#include <hip/hip_runtime.h>
#include <hip/hip_bf16.h>
#include <hip/hip_cooperative_groups.h>

namespace cg = cooperative_groups;

typedef __hip_bfloat16 bf16_t;
typedef __attribute__((ext_vector_type(4))) float f32x4;
typedef __attribute__((ext_vector_type(8))) __bf16 bf16x8;
typedef __attribute__((ext_vector_type(8))) short s16x8;
typedef __attribute__((ext_vector_type(4))) unsigned short u16x4;

#define BATCH 16384
#define NDIM  1024
#define HID   512
#define LAT   50

#define LOG2E 1.44269504088896340736f
#define RLOG2E 0.69314718055994530942f

__device__ __forceinline__ float ex2(float x) { return __builtin_amdgcn_exp2f(x); }
__device__ __forceinline__ float lg2(float x) { return __builtin_amdgcn_logf(x); }
__device__ __forceinline__ float rcp(float x) { return __builtin_amdgcn_rcpf(x); }

__device__ inline unsigned short f2b_u(float f) {
  union { bf16_t b; unsigned short u; } cv; cv.b = __float2bfloat16(f); return cv.u;
}

__device__ __forceinline__ void gload16(const void* src, void* dst_lds) {
  __builtin_amdgcn_global_load_lds(
      reinterpret_cast<const __attribute__((address_space(1))) void*>(
          reinterpret_cast<unsigned long long>(src)),
      reinterpret_cast<__attribute__((address_space(3))) void*>(
          static_cast<unsigned>(reinterpret_cast<unsigned long long>(dst_lds))),
      16, 0, 0);
}

#define WAIT_VMCNT(N)                                          \
  do {                                                         \
    asm volatile("s_waitcnt vmcnt(%0)" ::"i"(N) : "memory");   \
    __builtin_amdgcn_sched_barrier(0);                         \
  } while (0)
#define WAIT_LGKM0                                             \
  do {                                                         \
    asm volatile("s_waitcnt lgkmcnt(0)" ::: "memory");         \
    __builtin_amdgcn_sched_barrier(0);                         \
  } while (0)

// ---------------------------------------------------------------------------
// GEMM phase (R19 best-measured structure, verbatim): C = epi(A@B^T + bias).
// Tile BM x 256, BK=64, 8 waves (2M x 4N); front-loaded staging, one
// vmcnt(0)+barrier per K-tile; setprio around MFMA clusters.
// ---------------------------------------------------------------------------
template<int A_F32, int EPI, int BM>
__device__ __forceinline__
void gemm_phase(const void* __restrict__ Av, const bf16_t* __restrict__ B,
                const float* __restrict__ bias, void* __restrict__ out0,
                int N, int K, char* lds, int tid)
{
  constexpr int BN  = 256;
  constexpr int BUF = (BM + BN) * 128;        // 48KB / 64KB
  constexpr int RA  = BM / 64;
  constexpr int MI  = BM / 32;
  constexpr int FPQ = MI / 4;

  const int swzid = ((blockIdx.x & 7) * (gridDim.x >> 3)) + (blockIdx.x >> 3);
  const int nblocks = N / BN;
  const int bn   = swzid % nblocks;
  const int bm   = swzid / nblocks;
  const int wid  = tid >> 6;
  const int lane = tid & 63;
  const int l15  = lane & 15;
  const int l4   = lane >> 4;
  const int wm   = (wid >> 2) * (BM / 2);
  const int wn   = (wid & 3) * 64;
  const int uw   = __builtin_amdgcn_readfirstlane(wid);

  f32x4 acc[MI][4] = {};
  f32x4 areg[4];

  auto stage_A_round = [&](char* buf, int k0, int i) {
    const bf16_t* A = (const bf16_t*)Av;
    const int c  = (i * 8 + uw) * 64 + lane;
    const int r  = c >> 3;
    const int sp = c & 7;
    const int sl = sp ^ (r & 7);
    gload16(A + (size_t)(bm * BM + r) * K + k0 + sl * 8,
            buf + (i * 8 + uw) * 1024);
  };
  auto stage_B_round = [&](char* buf, int k0, int i) {
    char* lB = buf + BM * 128;
    const int c  = (i * 8 + uw) * 64 + lane;
    const int r  = c >> 3;
    const int sp = c & 7;
    const int sl = sp ^ (r & 7);
    gload16(B + (size_t)(bn * BN + r) * K + k0 + sl * 8,
            lB + (i * 8 + uw) * 1024);
  };
  auto load_A_f32 = [&](int k0) {
    const float* A = (const float*)Av;
    #pragma unroll
    for (int j = 0; j < 2; ++j) {
      const int c  = j * 512 + tid;
      const int r  = c >> 3;
      const int sl = c & 7;
      const float* s = A + (size_t)(bm * BM + r) * K + k0 + sl * 8;
      areg[2 * j]     = *(const f32x4*)s;
      areg[2 * j + 1] = *(const f32x4*)(s + 4);
    }
  };
  auto write_A_f32 = [&](char* buf) {
    #pragma unroll
    for (int j = 0; j < 2; ++j) {
      const int c  = j * 512 + tid;
      const int r  = c >> 3;
      const int sl = c & 7;
      const int sp = sl ^ (r & 7);
      union { s16x8 v; unsigned short us[8]; } o;
      const f32x4 v0 = areg[2 * j], v1 = areg[2 * j + 1];
      o.us[0]=f2b_u(v0[0]); o.us[1]=f2b_u(v0[1]); o.us[2]=f2b_u(v0[2]); o.us[3]=f2b_u(v0[3]);
      o.us[4]=f2b_u(v1[0]); o.us[5]=f2b_u(v1[1]); o.us[6]=f2b_u(v1[2]); o.us[7]=f2b_u(v1[3]);
      *(s16x8*)(buf + r * 128 + sp * 16) = o.v;
    }
  };

  const int nt = K >> 6;
  if constexpr (A_F32) {
    load_A_f32(0); write_A_f32(lds);
  } else {
    #pragma unroll
    for (int i = 0; i < RA; ++i) stage_A_round(lds, 0, i);
  }
  #pragma unroll
  for (int i = 0; i < 4; ++i) stage_B_round(lds, 0, i);
  WAIT_VMCNT(0);
  if (A_F32) WAIT_LGKM0;
  __builtin_amdgcn_s_barrier();

  for (int t = 0; t < nt; ++t) {
    char* buf  = lds + (t & 1) * BUF;
    char* nbuf = lds + ((t + 1) & 1) * BUF;
    const char* lA = buf;
    const char* lB = buf + BM * 128;
    const bool pf  = (t + 1 < nt);
    const int k0n  = (t + 1) << 6;

    if (pf) {
      if constexpr (A_F32) {
        load_A_f32(k0n);
      } else {
        #pragma unroll
        for (int i = 0; i < RA; ++i) stage_A_round(nbuf, k0n, i);
      }
      #pragma unroll
      for (int i = 0; i < 4; ++i) stage_B_round(nbuf, k0n, i);
    }

    bf16x8 bfr[4][2];
    #pragma unroll
    for (int ni = 0; ni < 4; ++ni)
      #pragma unroll
      for (int h = 0; h < 2; ++h) {
        const int row = wn + ni * 16 + l15;
        const int sp  = (h * 4 + l4) ^ (row & 7);
        bfr[ni][h] = *(const bf16x8*)(lB + row * 128 + sp * 16);
      }

    #pragma unroll
    for (int q = 0; q < 4; ++q) {
      bf16x8 af[FPQ][2];
      #pragma unroll
      for (int f = 0; f < FPQ; ++f)
        #pragma unroll
        for (int h = 0; h < 2; ++h) {
          const int row = wm + (q * FPQ + f) * 16 + l15;
          const int sp  = (h * 4 + l4) ^ (row & 7);
          af[f][h] = *(const bf16x8*)(lA + row * 128 + sp * 16);
        }
      __builtin_amdgcn_s_setprio(1);
      #pragma unroll
      for (int f = 0; f < FPQ; ++f)
        #pragma unroll
        for (int ni = 0; ni < 4; ++ni)
          #pragma unroll
          for (int h = 0; h < 2; ++h)
            acc[q * FPQ + f][ni] = __builtin_amdgcn_mfma_f32_16x16x32_bf16(
                af[f][h], bfr[ni][h], acc[q * FPQ + f][ni], 0, 0, 0);
      __builtin_amdgcn_s_setprio(0);
    }

    if (A_F32 && pf) write_A_f32(nbuf);
    WAIT_VMCNT(0);
    if (A_F32) WAIT_LGKM0;
    __builtin_amdgcn_s_barrier();
  }

  #pragma unroll
  for (int ni = 0; ni < 4; ++ni) {
    const int n  = bn * BN + wn + ni * 16 + l15;
    const float bv = bias[n];
    #pragma unroll
    for (int mi = 0; mi < MI; ++mi) {
      #pragma unroll
      for (int r = 0; r < 4; ++r) {
        const int m  = bm * BM + wm + mi * 16 + l4 * 4 + r;
        const float t = acc[mi][ni][r] + bv;
        if (EPI == 0) {
          ((bf16_t*)out0)[(size_t)m * N + n] = __float2bfloat16(fmaxf(t, 0.f));
        } else {
          ((float*)out0)[(size_t)m * N + n] = rcp(1.f + ex2(-t * LOG2E));
        }
      }
    }
  }
}

// ---------------------------------------------------------------------------
// MEGA cooperative kernel: prep -> GEMM1 -> abstick -> GEMM4 with grid.sync
// between phases (replaces 3 kernel-launch boundaries; grid 256 x 512,
// LDS 128KB -> exactly 1 block/CU x 256 CUs co-resident; grid.sync's
// device-scope fence gives cross-XCD visibility of h/h2 per G16).
// ---------------------------------------------------------------------------
__global__ __launch_bounds__(512, 1)
void mega_kernel(const float* __restrict__ x, const float* __restrict__ u,
                 const float* __restrict__ W1, const float* __restrict__ b1,
                 const float* __restrict__ Wa, const float* __restrict__ ba,
                 const float* __restrict__ Wb, const float* __restrict__ bb,
                 const float* __restrict__ W2, const float* __restrict__ b2,
                 const float* __restrict__ W3, const float* __restrict__ b3,
                 float* __restrict__ recon, float* __restrict__ oalpha,
                 float* __restrict__ obeta, bf16_t* __restrict__ h,
                 bf16_t* __restrict__ h2, bf16_t* __restrict__ w1,
                 bf16_t* __restrict__ w3, bf16_t* __restrict__ wab,
                 bf16_t* __restrict__ w2p, float* __restrict__ bab)
{
  cg::grid_group grid = cg::this_grid();
  __shared__ char lds[131072];                 // max phase (GEMM4: 2x64KB)
  const int tid = threadIdx.x;

  // ---- phase 0: prep (grid-stride over weights) ---------------------------
  {
    const int W1U  = (HID * NDIM) / 4;
    const int W3U  = (NDIM * HID) / 4;
    const int WABN = 128 * HID;
    const int W2PN = HID * 64;
    const int TOT  = W1U + W3U + WABN + W2PN + 128;
    for (int i = blockIdx.x * blockDim.x + tid; i < TOT;
         i += gridDim.x * blockDim.x) {
      int j = i;
      if (j < W1U) {
        const f32x4 v = ((const f32x4*)W1)[j];
        u16x4 o; o[0]=f2b_u(v[0]); o[1]=f2b_u(v[1]); o[2]=f2b_u(v[2]); o[3]=f2b_u(v[3]);
        ((u16x4*)w1)[j] = o; continue;
      }
      j -= W1U;
      if (j < W3U) {
        const f32x4 v = ((const f32x4*)W3)[j];
        u16x4 o; o[0]=f2b_u(v[0]); o[1]=f2b_u(v[1]); o[2]=f2b_u(v[2]); o[3]=f2b_u(v[3]);
        ((u16x4*)w3)[j] = o; continue;
      }
      j -= W3U;
      if (j < WABN) {
        const int n = j >> 9, k = j & 511;
        float v = (n < 50) ? Wa[n * 512 + k] : ((n < 100) ? Wb[(n - 50) * 512 + k] : 0.f);
        wab[j] = __float2bfloat16(v); continue;
      }
      j -= WABN;
      if (j < W2PN) {
        const int n = j >> 6, k = j & 63;
        w2p[j] = __float2bfloat16(k < 50 ? W2[n * 50 + k] : 0.f); continue;
      }
      j -= W2PN;
      bab[j] = (j < 50) ? ba[j] : ((j < 100) ? bb[j - 50] : 0.f);
    }
  }
  grid.sync();

  // ---- phase 1: h = relu(x @ W1^T + b1)  (BM=128, A=f32) ------------------
  gemm_phase<1, 0, 128>(x, w1, b1, (void*)h, HID, NDIM, lds, tid);
  grid.sync();

  // ---- phase 2: alpha/beta + stick + GEMM3 -> h2 --------------------------
  {
    constexpr int BUF = 64 * 128 + 16384;      // 24576
    constexpr int PIL = 65536;
    constexpr int SMO = 73728;
    const bf16_t* A = h;
    const int swzid = ((blockIdx.x & 7) * (gridDim.x >> 3)) + (blockIdx.x >> 3);
    const int bm   = swzid;
    const int wid  = tid >> 6;
    const int lane = tid & 63;
    const int l15  = lane & 15;
    const int l4   = lane >> 4;
    const int wm   = (wid >> 2) * 32;
    const int wn   = (wid & 3) * 32;
    const int uw   = __builtin_amdgcn_readfirstlane(wid);
    const int K    = HID;

    f32x4 acc[2][2] = {};

    auto stage_AB = [&](char* buf, int k0) {
      {
        const int c  = tid;
        const int r  = c >> 3;
        const int sp = c & 7;
        const int sl = sp ^ (r & 7);
        gload16(A + (size_t)(bm * 64 + r) * K + k0 + sl * 8, buf + uw * 1024);
      }
      char* lB = buf + 8192;
      #pragma unroll
      for (int i = 0; i < 2; ++i) {
        const int c  = (i * 8 + uw) * 64 + lane;
        const int r  = c >> 3;
        const int sp = c & 7;
        const int sl = sp ^ (r & 7);
        gload16(wab + (size_t)r * K + k0 + sl * 8, lB + (i * 8 + uw) * 1024);
      }
    };
    auto compute1 = [&](const char* buf) {
      const char* lA = buf;
      const char* lB = buf + 8192;
      #pragma unroll
      for (int hh = 0; hh < 2; ++hh) {
        bf16x8 af[2], bfr[2];
        #pragma unroll
        for (int mi = 0; mi < 2; ++mi) {
          const int row = wm + mi * 16 + l15;
          const int sp  = (hh * 4 + l4) ^ (row & 7);
          af[mi] = *(const bf16x8*)(lA + row * 128 + sp * 16);
        }
        #pragma unroll
        for (int ni = 0; ni < 2; ++ni) {
          const int row = wn + ni * 16 + l15;
          const int sp  = (hh * 4 + l4) ^ (row & 7);
          bfr[ni] = *(const bf16x8*)(lB + row * 128 + sp * 16);
        }
        #pragma unroll
        for (int mi = 0; mi < 2; ++mi)
          #pragma unroll
          for (int ni = 0; ni < 2; ++ni)
            acc[mi][ni] = __builtin_amdgcn_mfma_f32_16x16x32_bf16(
                af[mi], bfr[ni], acc[mi][ni], 0, 0, 0);
      }
    };

    stage_AB(lds, 0);
    stage_AB(lds + BUF, 64);
    for (int t = 0; t < 8; ++t) {
      if (t + 1 < 8) WAIT_VMCNT(3);
      else           WAIT_VMCNT(0);
      __builtin_amdgcn_s_barrier();
      compute1(lds + (t & 1) * BUF);
      __builtin_amdgcn_s_barrier();
      __builtin_amdgcn_sched_barrier(0);
      if (t + 2 < 8) stage_AB(lds + (t & 1) * BUF, (t + 2) << 6);
    }

    const int ul = (lane < 49) ? lane : 0;
    float ureg[8];
    #pragma unroll
    for (int rr = 0; rr < 8; ++rr) {
      const size_t m = (size_t)(bm * 64 + wid * 8 + rr);
      ureg[rr] = u[m * 50 + ul];
    }

    #pragma unroll
    for (int i = 0; i < 8; ++i) {
      const int c  = (i * 8 + uw) * 64 + lane;
      const int r  = c >> 3;
      const int sp = c & 7;
      const int sl = sp ^ (r & 7);
      gload16(w2p + (size_t)r * 64 + sl * 8, lds + (i * 8 + uw) * 1024);
    }

    float* sm = (float*)(lds + SMO);
    #pragma unroll
    for (int ni = 0; ni < 2; ++ni) {
      const int n  = wn + ni * 16 + l15;
      const float bv = bab[n];
      #pragma unroll
      for (int mi = 0; mi < 2; ++mi) {
        #pragma unroll
        for (int r = 0; r < 4; ++r) {
          const int ml = wm + mi * 16 + l4 * 4 + r;
          const int m  = bm * 64 + ml;
          const float t = acc[mi][ni][r] + bv;
          if (n < 100) {
            const float y =
                (t > 20.f ? t : lg2(1.f + ex2(t * LOG2E)) * RLOG2E) + 1e-4f;
            if (n < 50) oalpha[(size_t)m * 50 + n] = y;
            else        obeta[(size_t)m * 50 + (n - 50)] = y;
            sm[ml * 104 + n + (n < 50 ? 0 : 2)] = y;
          }
        }
      }
    }
    __syncthreads();

    #pragma unroll 1
    for (int rr = 0; rr < 8; ++rr) {
      const int rl = wid * 8 + rr;
      float v = 1.f, t = 1.f;
      if (lane < 49) {
        const float a  = sm[rl * 104 + lane];
        const float b  = sm[rl * 104 + 52 + lane];
        const float uu = ureg[rr];
        const float tb = ex2(lg2(uu) * rcp(b));
        v = ex2(lg2(1.f - tb) * rcp(a));
        t = 1.f - v;
      }
      float p = t;
      #pragma unroll
      for (int d = 1; d < 64; d <<= 1) {
        const float o = __shfl_up(p, d, 64);
        if (lane >= d) p *= o;
      }
      float e = __shfl_up(p, 1, 64);
      if (lane == 0) e = 1.f;
      const float piv = (lane < 50) ? v * e : 0.f;
      *(unsigned short*)(lds + PIL + rl * 128 +
                         (((lane >> 3) ^ (rl & 7)) << 4) + ((lane & 7) << 1)) =
          f2b_u(piv);
    }
    __syncthreads();

    const int wn3 = (wid & 3) * 128;
    f32x4 acc3[2][8] = {};
    #pragma unroll
    for (int hh = 0; hh < 2; ++hh) {
      bf16x8 af[2], bfr[8];
      #pragma unroll
      for (int mi = 0; mi < 2; ++mi) {
        const int row = wm + mi * 16 + l15;
        const int sp  = (hh * 4 + l4) ^ (row & 7);
        af[mi] = *(const bf16x8*)(lds + PIL + row * 128 + sp * 16);
      }
      #pragma unroll
      for (int ni = 0; ni < 8; ++ni) {
        const int row = wn3 + ni * 16 + l15;
        const int sp  = (hh * 4 + l4) ^ (row & 7);
        bfr[ni] = *(const bf16x8*)(lds + row * 128 + sp * 16);
      }
      #pragma unroll
      for (int mi = 0; mi < 2; ++mi)
        #pragma unroll
        for (int ni = 0; ni < 8; ++ni)
          acc3[mi][ni] = __builtin_amdgcn_mfma_f32_16x16x32_bf16(
              af[mi], bfr[ni], acc3[mi][ni], 0, 0, 0);
    }
    #pragma unroll
    for (int ni = 0; ni < 8; ++ni) {
      const int n  = wn3 + ni * 16 + l15;
      const float bv = b2[n];
      #pragma unroll
      for (int mi = 0; mi < 2; ++mi) {
        #pragma unroll
        for (int r = 0; r < 4; ++r) {
          const int m  = bm * 64 + wm + mi * 16 + l4 * 4 + r;
          h2[(size_t)m * HID + n] =
              __float2bfloat16(fmaxf(acc3[mi][ni][r] + bv, 0.f));
        }
      }
    }
  }
  grid.sync();

  // ---- phase 3: recon = sigmoid(h2 @ W3^T + b3)  (BM=256) -----------------
  gemm_phase<0, 1, 256>(h2, w3, b3, (void*)recon, NDIM, HID, lds, tid);
}

// ---------------------------------------------------------------------------
extern "C" void kernel_launch(void* const* d_in, const int* in_sizes, int n_in,
                              void* d_out, int out_size, void* d_ws, size_t ws_size,
                              hipStream_t stream)
{
  const float* x  = (const float*)d_in[0];
  const float* u  = (const float*)d_in[1];
  const float* W1 = (const float*)d_in[2];
  const float* b1 = (const float*)d_in[3];
  const float* Wa = (const float*)d_in[4];
  const float* ba = (const float*)d_in[5];
  const float* Wb = (const float*)d_in[6];
  const float* bb = (const float*)d_in[7];
  const float* W2 = (const float*)d_in[8];
  const float* b2 = (const float*)d_in[9];
  const float* W3 = (const float*)d_in[10];
  const float* b3 = (const float*)d_in[11];

  float* recon  = (float*)d_out;
  float* oalpha = recon + (size_t)BATCH * NDIM;
  float* obeta  = oalpha + (size_t)BATCH * LAT;

  char* ws = (char*)d_ws;
  bf16_t* h2  = (bf16_t*)(ws);                 // 16,777,216
  bf16_t* h   = (bf16_t*)(ws + 16777216);      // 16,777,216
  bf16_t* w1  = (bf16_t*)(ws + 33554432);      //  1,048,576
  bf16_t* w3  = (bf16_t*)(ws + 34603008);      //  1,048,576
  bf16_t* wab = (bf16_t*)(ws + 35651584);      //    131,072
  bf16_t* w2p = (bf16_t*)(ws + 35782656);      //     65,536
  float*  bab = (float*)(ws + 35848192);       //        512

  void* kargs[] = {
      (void*)&x,  (void*)&u,  (void*)&W1, (void*)&b1, (void*)&Wa, (void*)&ba,
      (void*)&Wb, (void*)&bb, (void*)&W2, (void*)&b2, (void*)&W3, (void*)&b3,
      (void*)&recon, (void*)&oalpha, (void*)&obeta, (void*)&h, (void*)&h2,
      (void*)&w1, (void*)&w3, (void*)&wab, (void*)&w2p, (void*)&bab};
  hipLaunchCooperativeKernel((const void*)mega_kernel, dim3(256), dim3(512),
                             kargs, 0, stream);
}

// Round 23
// 179.628 us; speedup vs baseline: 1.0062x; 1.0062x over previous
//
#include <hip/hip_runtime.h>
#include <hip/hip_bf16.h>
#include <hip/hip_cooperative_groups.h>

namespace cg = cooperative_groups;

typedef __hip_bfloat16 bf16_t;
typedef __attribute__((ext_vector_type(4))) float f32x4;
typedef __attribute__((ext_vector_type(8))) __bf16 bf16x8;
typedef __attribute__((ext_vector_type(8))) short s16x8;
typedef __attribute__((ext_vector_type(4))) unsigned short u16x4;

#define BATCH 16384
#define NDIM  1024
#define HID   512
#define LAT   50

#define LOG2E 1.44269504088896340736f
#define RLOG2E 0.69314718055994530942f

__device__ __forceinline__ float ex2(float x) { return __builtin_amdgcn_exp2f(x); }
__device__ __forceinline__ float lg2(float x) { return __builtin_amdgcn_logf(x); }
__device__ __forceinline__ float rcp(float x) { return __builtin_amdgcn_rcpf(x); }

__device__ inline unsigned short f2b_u(float f) {
  union { bf16_t b; unsigned short u; } cv; cv.b = __float2bfloat16(f); return cv.u;
}

__device__ __forceinline__ void gload16(const void* src, void* dst_lds) {
  __builtin_amdgcn_global_load_lds(
      reinterpret_cast<const __attribute__((address_space(1))) void*>(
          reinterpret_cast<unsigned long long>(src)),
      reinterpret_cast<__attribute__((address_space(3))) void*>(
          static_cast<unsigned>(reinterpret_cast<unsigned long long>(dst_lds))),
      16, 0, 0);
}

#define WAIT_VMCNT(N)                                          \
  do {                                                         \
    asm volatile("s_waitcnt vmcnt(%0)" ::"i"(N) : "memory");   \
    __builtin_amdgcn_sched_barrier(0);                         \
  } while (0)
#define WAIT_LGKM0                                             \
  do {                                                         \
    asm volatile("s_waitcnt lgkmcnt(0)" ::: "memory");         \
    __builtin_amdgcn_sched_barrier(0);                         \
  } while (0)

// ---------------------------------------------------------------------------
// GEMM phase (R19 best-measured structure, verbatim): C = epi(A@B^T + bias).
// Tile BM x 256, BK=64, 8 waves (2M x 4N); front-loaded staging, one
// vmcnt(0)+barrier per K-tile; setprio around MFMA clusters.
// ---------------------------------------------------------------------------
template<int A_F32, int EPI, int BM>
__device__ __forceinline__
void gemm_phase(const void* __restrict__ Av, const bf16_t* __restrict__ B,
                const float* __restrict__ bias, void* __restrict__ out0,
                int N, int K, char* lds, int tid)
{
  constexpr int BN  = 256;
  constexpr int BUF = (BM + BN) * 128;        // 48KB / 64KB
  constexpr int RA  = BM / 64;
  constexpr int MI  = BM / 32;
  constexpr int FPQ = MI / 4;

  const int swzid = ((blockIdx.x & 7) * (gridDim.x >> 3)) + (blockIdx.x >> 3);
  const int nblocks = N / BN;
  const int bn   = swzid % nblocks;
  const int bm   = swzid / nblocks;
  const int wid  = tid >> 6;
  const int lane = tid & 63;
  const int l15  = lane & 15;
  const int l4   = lane >> 4;
  const int wm   = (wid >> 2) * (BM / 2);
  const int wn   = (wid & 3) * 64;
  const int uw   = __builtin_amdgcn_readfirstlane(wid);

  f32x4 acc[MI][4] = {};
  f32x4 areg[4];

  auto stage_A_round = [&](char* buf, int k0, int i) {
    const bf16_t* A = (const bf16_t*)Av;
    const int c  = (i * 8 + uw) * 64 + lane;
    const int r  = c >> 3;
    const int sp = c & 7;
    const int sl = sp ^ (r & 7);
    gload16(A + (size_t)(bm * BM + r) * K + k0 + sl * 8,
            buf + (i * 8 + uw) * 1024);
  };
  auto stage_B_round = [&](char* buf, int k0, int i) {
    char* lB = buf + BM * 128;
    const int c  = (i * 8 + uw) * 64 + lane;
    const int r  = c >> 3;
    const int sp = c & 7;
    const int sl = sp ^ (r & 7);
    gload16(B + (size_t)(bn * BN + r) * K + k0 + sl * 8,
            lB + (i * 8 + uw) * 1024);
  };
  auto load_A_f32 = [&](int k0) {
    const float* A = (const float*)Av;
    #pragma unroll
    for (int j = 0; j < 2; ++j) {
      const int c  = j * 512 + tid;
      const int r  = c >> 3;
      const int sl = c & 7;
      const float* s = A + (size_t)(bm * BM + r) * K + k0 + sl * 8;
      areg[2 * j]     = *(const f32x4*)s;
      areg[2 * j + 1] = *(const f32x4*)(s + 4);
    }
  };
  auto write_A_f32 = [&](char* buf) {
    #pragma unroll
    for (int j = 0; j < 2; ++j) {
      const int c  = j * 512 + tid;
      const int r  = c >> 3;
      const int sl = c & 7;
      const int sp = sl ^ (r & 7);
      union { s16x8 v; unsigned short us[8]; } o;
      const f32x4 v0 = areg[2 * j], v1 = areg[2 * j + 1];
      o.us[0]=f2b_u(v0[0]); o.us[1]=f2b_u(v0[1]); o.us[2]=f2b_u(v0[2]); o.us[3]=f2b_u(v0[3]);
      o.us[4]=f2b_u(v1[0]); o.us[5]=f2b_u(v1[1]); o.us[6]=f2b_u(v1[2]); o.us[7]=f2b_u(v1[3]);
      *(s16x8*)(buf + r * 128 + sp * 16) = o.v;
    }
  };

  const int nt = K >> 6;
  if constexpr (A_F32) {
    load_A_f32(0); write_A_f32(lds);
  } else {
    #pragma unroll
    for (int i = 0; i < RA; ++i) stage_A_round(lds, 0, i);
  }
  #pragma unroll
  for (int i = 0; i < 4; ++i) stage_B_round(lds, 0, i);
  WAIT_VMCNT(0);
  if (A_F32) WAIT_LGKM0;
  __builtin_amdgcn_s_barrier();

  for (int t = 0; t < nt; ++t) {
    char* buf  = lds + (t & 1) * BUF;
    char* nbuf = lds + ((t + 1) & 1) * BUF;
    const char* lA = buf;
    const char* lB = buf + BM * 128;
    const bool pf  = (t + 1 < nt);
    const int k0n  = (t + 1) << 6;

    if (pf) {
      if constexpr (A_F32) {
        load_A_f32(k0n);
      } else {
        #pragma unroll
        for (int i = 0; i < RA; ++i) stage_A_round(nbuf, k0n, i);
      }
      #pragma unroll
      for (int i = 0; i < 4; ++i) stage_B_round(nbuf, k0n, i);
    }

    bf16x8 bfr[4][2];
    #pragma unroll
    for (int ni = 0; ni < 4; ++ni)
      #pragma unroll
      for (int h = 0; h < 2; ++h) {
        const int row = wn + ni * 16 + l15;
        const int sp  = (h * 4 + l4) ^ (row & 7);
        bfr[ni][h] = *(const bf16x8*)(lB + row * 128 + sp * 16);
      }

    #pragma unroll
    for (int q = 0; q < 4; ++q) {
      bf16x8 af[FPQ][2];
      #pragma unroll
      for (int f = 0; f < FPQ; ++f)
        #pragma unroll
        for (int h = 0; h < 2; ++h) {
          const int row = wm + (q * FPQ + f) * 16 + l15;
          const int sp  = (h * 4 + l4) ^ (row & 7);
          af[f][h] = *(const bf16x8*)(lA + row * 128 + sp * 16);
        }
      __builtin_amdgcn_s_setprio(1);
      #pragma unroll
      for (int f = 0; f < FPQ; ++f)
        #pragma unroll
        for (int ni = 0; ni < 4; ++ni)
          #pragma unroll
          for (int h = 0; h < 2; ++h)
            acc[q * FPQ + f][ni] = __builtin_amdgcn_mfma_f32_16x16x32_bf16(
                af[f][h], bfr[ni][h], acc[q * FPQ + f][ni], 0, 0, 0);
      __builtin_amdgcn_s_setprio(0);
    }

    if (A_F32 && pf) write_A_f32(nbuf);
    WAIT_VMCNT(0);
    if (A_F32) WAIT_LGKM0;
    __builtin_amdgcn_s_barrier();
  }

  #pragma unroll
  for (int ni = 0; ni < 4; ++ni) {
    const int n  = bn * BN + wn + ni * 16 + l15;
    const float bv = bias[n];
    #pragma unroll
    for (int mi = 0; mi < MI; ++mi) {
      #pragma unroll
      for (int r = 0; r < 4; ++r) {
        const int m  = bm * BM + wm + mi * 16 + l4 * 4 + r;
        const float t = acc[mi][ni][r] + bv;
        if (EPI == 0) {
          ((bf16_t*)out0)[(size_t)m * N + n] = __float2bfloat16(fmaxf(t, 0.f));
        } else {
          ((float*)out0)[(size_t)m * N + n] = rcp(1.f + ex2(-t * LOG2E));
        }
      }
    }
  }
}

// ---------------------------------------------------------------------------
// MEGA cooperative kernel: prep -> GEMM1 -> abstick -> GEMM4 with grid.sync
// between phases (replaces 3 kernel-launch boundaries; grid 256 x 512,
// LDS 128KB -> exactly 1 block/CU x 256 CUs co-resident; grid.sync's
// device-scope fence gives cross-XCD visibility of h/h2 per G16).
// ---------------------------------------------------------------------------
__global__ __launch_bounds__(512, 1)
void mega_kernel(const float* __restrict__ x, const float* __restrict__ u,
                 const float* __restrict__ W1, const float* __restrict__ b1,
                 const float* __restrict__ Wa, const float* __restrict__ ba,
                 const float* __restrict__ Wb, const float* __restrict__ bb,
                 const float* __restrict__ W2, const float* __restrict__ b2,
                 const float* __restrict__ W3, const float* __restrict__ b3,
                 float* __restrict__ recon, float* __restrict__ oalpha,
                 float* __restrict__ obeta, bf16_t* __restrict__ h,
                 bf16_t* __restrict__ h2, bf16_t* __restrict__ w1,
                 bf16_t* __restrict__ w3, bf16_t* __restrict__ wab,
                 bf16_t* __restrict__ w2p, float* __restrict__ bab)
{
  cg::grid_group grid = cg::this_grid();
  __shared__ char lds[131072];                 // max phase (GEMM4: 2x64KB)
  const int tid = threadIdx.x;

  // ---- phase 0: prep (grid-stride over weights) ---------------------------
  {
    const int W1U  = (HID * NDIM) / 4;
    const int W3U  = (NDIM * HID) / 4;
    const int WABN = 128 * HID;
    const int W2PN = HID * 64;
    const int TOT  = W1U + W3U + WABN + W2PN + 128;
    for (int i = blockIdx.x * blockDim.x + tid; i < TOT;
         i += gridDim.x * blockDim.x) {
      int j = i;
      if (j < W1U) {
        const f32x4 v = ((const f32x4*)W1)[j];
        u16x4 o; o[0]=f2b_u(v[0]); o[1]=f2b_u(v[1]); o[2]=f2b_u(v[2]); o[3]=f2b_u(v[3]);
        ((u16x4*)w1)[j] = o; continue;
      }
      j -= W1U;
      if (j < W3U) {
        const f32x4 v = ((const f32x4*)W3)[j];
        u16x4 o; o[0]=f2b_u(v[0]); o[1]=f2b_u(v[1]); o[2]=f2b_u(v[2]); o[3]=f2b_u(v[3]);
        ((u16x4*)w3)[j] = o; continue;
      }
      j -= W3U;
      if (j < WABN) {
        const int n = j >> 9, k = j & 511;
        float v = (n < 50) ? Wa[n * 512 + k] : ((n < 100) ? Wb[(n - 50) * 512 + k] : 0.f);
        wab[j] = __float2bfloat16(v); continue;
      }
      j -= WABN;
      if (j < W2PN) {
        const int n = j >> 6, k = j & 63;
        w2p[j] = __float2bfloat16(k < 50 ? W2[n * 50 + k] : 0.f); continue;
      }
      j -= W2PN;
      bab[j] = (j < 50) ? ba[j] : ((j < 100) ? bb[j - 50] : 0.f);
    }
  }
  grid.sync();

  // ---- phase 1: h = relu(x @ W1^T + b1)  (BM=128, A=f32) ------------------
  gemm_phase<1, 0, 128>(x, w1, b1, (void*)h, HID, NDIM, lds, tid);
  grid.sync();

  // ---- phase 2: alpha/beta + stick + GEMM3 -> h2 --------------------------
  {
    constexpr int BUF = 64 * 128 + 16384;      // 24576
    constexpr int PIL = 65536;
    constexpr int SMO = 73728;
    const bf16_t* A = h;
    const int swzid = ((blockIdx.x & 7) * (gridDim.x >> 3)) + (blockIdx.x >> 3);
    const int bm   = swzid;
    const int wid  = tid >> 6;
    const int lane = tid & 63;
    const int l15  = lane & 15;
    const int l4   = lane >> 4;
    const int wm   = (wid >> 2) * 32;
    const int wn   = (wid & 3) * 32;
    const int uw   = __builtin_amdgcn_readfirstlane(wid);
    const int K    = HID;

    f32x4 acc[2][2] = {};

    auto stage_AB = [&](char* buf, int k0) {
      {
        const int c  = tid;
        const int r  = c >> 3;
        const int sp = c & 7;
        const int sl = sp ^ (r & 7);
        gload16(A + (size_t)(bm * 64 + r) * K + k0 + sl * 8, buf + uw * 1024);
      }
      char* lB = buf + 8192;
      #pragma unroll
      for (int i = 0; i < 2; ++i) {
        const int c  = (i * 8 + uw) * 64 + lane;
        const int r  = c >> 3;
        const int sp = c & 7;
        const int sl = sp ^ (r & 7);
        gload16(wab + (size_t)r * K + k0 + sl * 8, lB + (i * 8 + uw) * 1024);
      }
    };
    auto compute1 = [&](const char* buf) {
      const char* lA = buf;
      const char* lB = buf + 8192;
      #pragma unroll
      for (int hh = 0; hh < 2; ++hh) {
        bf16x8 af[2], bfr[2];
        #pragma unroll
        for (int mi = 0; mi < 2; ++mi) {
          const int row = wm + mi * 16 + l15;
          const int sp  = (hh * 4 + l4) ^ (row & 7);
          af[mi] = *(const bf16x8*)(lA + row * 128 + sp * 16);
        }
        #pragma unroll
        for (int ni = 0; ni < 2; ++ni) {
          const int row = wn + ni * 16 + l15;
          const int sp  = (hh * 4 + l4) ^ (row & 7);
          bfr[ni] = *(const bf16x8*)(lB + row * 128 + sp * 16);
        }
        #pragma unroll
        for (int mi = 0; mi < 2; ++mi)
          #pragma unroll
          for (int ni = 0; ni < 2; ++ni)
            acc[mi][ni] = __builtin_amdgcn_mfma_f32_16x16x32_bf16(
                af[mi], bfr[ni], acc[mi][ni], 0, 0, 0);
      }
    };

    stage_AB(lds, 0);
    stage_AB(lds + BUF, 64);
    for (int t = 0; t < 8; ++t) {
      if (t + 1 < 8) WAIT_VMCNT(3);
      else           WAIT_VMCNT(0);
      __builtin_amdgcn_s_barrier();
      compute1(lds + (t & 1) * BUF);
      __builtin_amdgcn_s_barrier();
      __builtin_amdgcn_sched_barrier(0);
      if (t + 2 < 8) stage_AB(lds + (t & 1) * BUF, (t + 2) << 6);
    }

    const int ul = (lane < 49) ? lane : 0;
    float ureg[8];
    #pragma unroll
    for (int rr = 0; rr < 8; ++rr) {
      const size_t m = (size_t)(bm * 64 + wid * 8 + rr);
      ureg[rr] = u[m * 50 + ul];
    }

    #pragma unroll
    for (int i = 0; i < 8; ++i) {
      const int c  = (i * 8 + uw) * 64 + lane;
      const int r  = c >> 3;
      const int sp = c & 7;
      const int sl = sp ^ (r & 7);
      gload16(w2p + (size_t)r * 64 + sl * 8, lds + (i * 8 + uw) * 1024);
    }

    float* sm = (float*)(lds + SMO);
    #pragma unroll
    for (int ni = 0; ni < 2; ++ni) {
      const int n  = wn + ni * 16 + l15;
      const float bv = bab[n];
      #pragma unroll
      for (int mi = 0; mi < 2; ++mi) {
        #pragma unroll
        for (int r = 0; r < 4; ++r) {
          const int ml = wm + mi * 16 + l4 * 4 + r;
          const int m  = bm * 64 + ml;
          const float t = acc[mi][ni][r] + bv;
          if (n < 100) {
            const float y =
                (t > 20.f ? t : lg2(1.f + ex2(t * LOG2E)) * RLOG2E) + 1e-4f;
            if (n < 50) oalpha[(size_t)m * 50 + n] = y;
            else        obeta[(size_t)m * 50 + (n - 50)] = y;
            sm[ml * 104 + n + (n < 50 ? 0 : 2)] = y;
          }
        }
      }
    }
    __syncthreads();

    #pragma unroll 1
    for (int rr = 0; rr < 8; ++rr) {
      const int rl = wid * 8 + rr;
      float v = 1.f, t = 1.f;
      if (lane < 49) {
        const float a  = sm[rl * 104 + lane];
        const float b  = sm[rl * 104 + 52 + lane];
        const float uu = ureg[rr];
        const float tb = ex2(lg2(uu) * rcp(b));
        v = ex2(lg2(1.f - tb) * rcp(a));
        t = 1.f - v;
      }
      float p = t;
      #pragma unroll
      for (int d = 1; d < 64; d <<= 1) {
        const float o = __shfl_up(p, d, 64);
        if (lane >= d) p *= o;
      }
      float e = __shfl_up(p, 1, 64);
      if (lane == 0) e = 1.f;
      const float piv = (lane < 50) ? v * e : 0.f;
      *(unsigned short*)(lds + PIL + rl * 128 +
                         (((lane >> 3) ^ (rl & 7)) << 4) + ((lane & 7) << 1)) =
          f2b_u(piv);
    }
    __syncthreads();

    const int wn3 = (wid & 3) * 128;
    f32x4 acc3[2][8] = {};
    #pragma unroll
    for (int hh = 0; hh < 2; ++hh) {
      bf16x8 af[2], bfr[8];
      #pragma unroll
      for (int mi = 0; mi < 2; ++mi) {
        const int row = wm + mi * 16 + l15;
        const int sp  = (hh * 4 + l4) ^ (row & 7);
        af[mi] = *(const bf16x8*)(lds + PIL + row * 128 + sp * 16);
      }
      #pragma unroll
      for (int ni = 0; ni < 8; ++ni) {
        const int row = wn3 + ni * 16 + l15;
        const int sp  = (hh * 4 + l4) ^ (row & 7);
        bfr[ni] = *(const bf16x8*)(lds + row * 128 + sp * 16);
      }
      #pragma unroll
      for (int mi = 0; mi < 2; ++mi)
        #pragma unroll
        for (int ni = 0; ni < 8; ++ni)
          acc3[mi][ni] = __builtin_amdgcn_mfma_f32_16x16x32_bf16(
              af[mi], bfr[ni], acc3[mi][ni], 0, 0, 0);
    }
    #pragma unroll
    for (int ni = 0; ni < 8; ++ni) {
      const int n  = wn3 + ni * 16 + l15;
      const float bv = b2[n];
      #pragma unroll
      for (int mi = 0; mi < 2; ++mi) {
        #pragma unroll
        for (int r = 0; r < 4; ++r) {
          const int m  = bm * 64 + wm + mi * 16 + l4 * 4 + r;
          h2[(size_t)m * HID + n] =
              __float2bfloat16(fmaxf(acc3[mi][ni][r] + bv, 0.f));
        }
      }
    }
  }
  grid.sync();

  // ---- phase 3: recon = sigmoid(h2 @ W3^T + b3)  (BM=256) -----------------
  gemm_phase<0, 1, 256>(h2, w3, b3, (void*)recon, NDIM, HID, lds, tid);
}

// ---------------------------------------------------------------------------
extern "C" void kernel_launch(void* const* d_in, const int* in_sizes, int n_in,
                              void* d_out, int out_size, void* d_ws, size_t ws_size,
                              hipStream_t stream)
{
  const float* x  = (const float*)d_in[0];
  const float* u  = (const float*)d_in[1];
  const float* W1 = (const float*)d_in[2];
  const float* b1 = (const float*)d_in[3];
  const float* Wa = (const float*)d_in[4];
  const float* ba = (const float*)d_in[5];
  const float* Wb = (const float*)d_in[6];
  const float* bb = (const float*)d_in[7];
  const float* W2 = (const float*)d_in[8];
  const float* b2 = (const float*)d_in[9];
  const float* W3 = (const float*)d_in[10];
  const float* b3 = (const float*)d_in[11];

  float* recon  = (float*)d_out;
  float* oalpha = recon + (size_t)BATCH * NDIM;
  float* obeta  = oalpha + (size_t)BATCH * LAT;

  char* ws = (char*)d_ws;
  bf16_t* h2  = (bf16_t*)(ws);                 // 16,777,216
  bf16_t* h   = (bf16_t*)(ws + 16777216);      // 16,777,216
  bf16_t* w1  = (bf16_t*)(ws + 33554432);      //  1,048,576
  bf16_t* w3  = (bf16_t*)(ws + 34603008);      //  1,048,576
  bf16_t* wab = (bf16_t*)(ws + 35651584);      //    131,072
  bf16_t* w2p = (bf16_t*)(ws + 35782656);      //     65,536
  float*  bab = (float*)(ws + 35848192);       //        512

  void* kargs[] = {
      (void*)&x,  (void*)&u,  (void*)&W1, (void*)&b1, (void*)&Wa, (void*)&ba,
      (void*)&Wb, (void*)&bb, (void*)&W2, (void*)&b2, (void*)&W3, (void*)&b3,
      (void*)&recon, (void*)&oalpha, (void*)&obeta, (void*)&h, (void*)&h2,
      (void*)&w1, (void*)&w3, (void*)&wab, (void*)&w2p, (void*)&bab};
  hipLaunchCooperativeKernel((const void*)mega_kernel, dim3(256), dim3(512),
                             kargs, 0, stream);
}

// Round 24
// 179.605 us; speedup vs baseline: 1.0063x; 1.0001x over previous
//
#include <hip/hip_runtime.h>
#include <hip/hip_bf16.h>
#include <hip/hip_cooperative_groups.h>

namespace cg = cooperative_groups;

typedef __hip_bfloat16 bf16_t;
typedef __attribute__((ext_vector_type(4))) float f32x4;
typedef __attribute__((ext_vector_type(8))) __bf16 bf16x8;
typedef __attribute__((ext_vector_type(8))) short s16x8;
typedef __attribute__((ext_vector_type(4))) unsigned short u16x4;

#define BATCH 16384
#define NDIM  1024
#define HID   512
#define LAT   50

#define LOG2E 1.44269504088896340736f
#define RLOG2E 0.69314718055994530942f

__device__ __forceinline__ float ex2(float x) { return __builtin_amdgcn_exp2f(x); }
__device__ __forceinline__ float lg2(float x) { return __builtin_amdgcn_logf(x); }
__device__ __forceinline__ float rcp(float x) { return __builtin_amdgcn_rcpf(x); }

__device__ inline unsigned short f2b_u(float f) {
  union { bf16_t b; unsigned short u; } cv; cv.b = __float2bfloat16(f); return cv.u;
}

__device__ __forceinline__ void gload16(const void* src, void* dst_lds) {
  __builtin_amdgcn_global_load_lds(
      reinterpret_cast<const __attribute__((address_space(1))) void*>(
          reinterpret_cast<unsigned long long>(src)),
      reinterpret_cast<__attribute__((address_space(3))) void*>(
          static_cast<unsigned>(reinterpret_cast<unsigned long long>(dst_lds))),
      16, 0, 0);
}

#define WAIT_VMCNT(N)                                          \
  do {                                                         \
    asm volatile("s_waitcnt vmcnt(%0)" ::"i"(N) : "memory");   \
    __builtin_amdgcn_sched_barrier(0);                         \
  } while (0)
#define WAIT_LGKM0                                             \
  do {                                                         \
    asm volatile("s_waitcnt lgkmcnt(0)" ::: "memory");         \
    __builtin_amdgcn_sched_barrier(0);                         \
  } while (0)

// ---------------------------------------------------------------------------
// GEMM phase (R19 best-measured structure, verbatim): C = epi(A@B^T + bias).
// Tile BM x 256, BK=64, 8 waves (2M x 4N); front-loaded staging, one
// vmcnt(0)+barrier per K-tile; setprio around MFMA clusters.
// ---------------------------------------------------------------------------
template<int A_F32, int EPI, int BM>
__device__ __forceinline__
void gemm_phase(const void* __restrict__ Av, const bf16_t* __restrict__ B,
                const float* __restrict__ bias, void* __restrict__ out0,
                int N, int K, char* lds, int tid)
{
  constexpr int BN  = 256;
  constexpr int BUF = (BM + BN) * 128;        // 48KB / 64KB
  constexpr int RA  = BM / 64;
  constexpr int MI  = BM / 32;
  constexpr int FPQ = MI / 4;

  const int swzid = ((blockIdx.x & 7) * (gridDim.x >> 3)) + (blockIdx.x >> 3);
  const int nblocks = N / BN;
  const int bn   = swzid % nblocks;
  const int bm   = swzid / nblocks;
  const int wid  = tid >> 6;
  const int lane = tid & 63;
  const int l15  = lane & 15;
  const int l4   = lane >> 4;
  const int wm   = (wid >> 2) * (BM / 2);
  const int wn   = (wid & 3) * 64;
  const int uw   = __builtin_amdgcn_readfirstlane(wid);

  f32x4 acc[MI][4] = {};
  f32x4 areg[4];

  auto stage_A_round = [&](char* buf, int k0, int i) {
    const bf16_t* A = (const bf16_t*)Av;
    const int c  = (i * 8 + uw) * 64 + lane;
    const int r  = c >> 3;
    const int sp = c & 7;
    const int sl = sp ^ (r & 7);
    gload16(A + (size_t)(bm * BM + r) * K + k0 + sl * 8,
            buf + (i * 8 + uw) * 1024);
  };
  auto stage_B_round = [&](char* buf, int k0, int i) {
    char* lB = buf + BM * 128;
    const int c  = (i * 8 + uw) * 64 + lane;
    const int r  = c >> 3;
    const int sp = c & 7;
    const int sl = sp ^ (r & 7);
    gload16(B + (size_t)(bn * BN + r) * K + k0 + sl * 8,
            lB + (i * 8 + uw) * 1024);
  };
  auto load_A_f32 = [&](int k0) {
    const float* A = (const float*)Av;
    #pragma unroll
    for (int j = 0; j < 2; ++j) {
      const int c  = j * 512 + tid;
      const int r  = c >> 3;
      const int sl = c & 7;
      const float* s = A + (size_t)(bm * BM + r) * K + k0 + sl * 8;
      areg[2 * j]     = *(const f32x4*)s;
      areg[2 * j + 1] = *(const f32x4*)(s + 4);
    }
  };
  auto write_A_f32 = [&](char* buf) {
    #pragma unroll
    for (int j = 0; j < 2; ++j) {
      const int c  = j * 512 + tid;
      const int r  = c >> 3;
      const int sl = c & 7;
      const int sp = sl ^ (r & 7);
      union { s16x8 v; unsigned short us[8]; } o;
      const f32x4 v0 = areg[2 * j], v1 = areg[2 * j + 1];
      o.us[0]=f2b_u(v0[0]); o.us[1]=f2b_u(v0[1]); o.us[2]=f2b_u(v0[2]); o.us[3]=f2b_u(v0[3]);
      o.us[4]=f2b_u(v1[0]); o.us[5]=f2b_u(v1[1]); o.us[6]=f2b_u(v1[2]); o.us[7]=f2b_u(v1[3]);
      *(s16x8*)(buf + r * 128 + sp * 16) = o.v;
    }
  };

  const int nt = K >> 6;
  if constexpr (A_F32) {
    load_A_f32(0); write_A_f32(lds);
  } else {
    #pragma unroll
    for (int i = 0; i < RA; ++i) stage_A_round(lds, 0, i);
  }
  #pragma unroll
  for (int i = 0; i < 4; ++i) stage_B_round(lds, 0, i);
  WAIT_VMCNT(0);
  if (A_F32) WAIT_LGKM0;
  __builtin_amdgcn_s_barrier();

  for (int t = 0; t < nt; ++t) {
    char* buf  = lds + (t & 1) * BUF;
    char* nbuf = lds + ((t + 1) & 1) * BUF;
    const char* lA = buf;
    const char* lB = buf + BM * 128;
    const bool pf  = (t + 1 < nt);
    const int k0n  = (t + 1) << 6;

    if (pf) {
      if constexpr (A_F32) {
        load_A_f32(k0n);
      } else {
        #pragma unroll
        for (int i = 0; i < RA; ++i) stage_A_round(nbuf, k0n, i);
      }
      #pragma unroll
      for (int i = 0; i < 4; ++i) stage_B_round(nbuf, k0n, i);
    }

    bf16x8 bfr[4][2];
    #pragma unroll
    for (int ni = 0; ni < 4; ++ni)
      #pragma unroll
      for (int h = 0; h < 2; ++h) {
        const int row = wn + ni * 16 + l15;
        const int sp  = (h * 4 + l4) ^ (row & 7);
        bfr[ni][h] = *(const bf16x8*)(lB + row * 128 + sp * 16);
      }

    #pragma unroll
    for (int q = 0; q < 4; ++q) {
      bf16x8 af[FPQ][2];
      #pragma unroll
      for (int f = 0; f < FPQ; ++f)
        #pragma unroll
        for (int h = 0; h < 2; ++h) {
          const int row = wm + (q * FPQ + f) * 16 + l15;
          const int sp  = (h * 4 + l4) ^ (row & 7);
          af[f][h] = *(const bf16x8*)(lA + row * 128 + sp * 16);
        }
      __builtin_amdgcn_s_setprio(1);
      #pragma unroll
      for (int f = 0; f < FPQ; ++f)
        #pragma unroll
        for (int ni = 0; ni < 4; ++ni)
          #pragma unroll
          for (int h = 0; h < 2; ++h)
            acc[q * FPQ + f][ni] = __builtin_amdgcn_mfma_f32_16x16x32_bf16(
                af[f][h], bfr[ni][h], acc[q * FPQ + f][ni], 0, 0, 0);
      __builtin_amdgcn_s_setprio(0);
    }

    if (A_F32 && pf) write_A_f32(nbuf);
    WAIT_VMCNT(0);
    if (A_F32) WAIT_LGKM0;
    __builtin_amdgcn_s_barrier();
  }

  #pragma unroll
  for (int ni = 0; ni < 4; ++ni) {
    const int n  = bn * BN + wn + ni * 16 + l15;
    const float bv = bias[n];
    #pragma unroll
    for (int mi = 0; mi < MI; ++mi) {
      #pragma unroll
      for (int r = 0; r < 4; ++r) {
        const int m  = bm * BM + wm + mi * 16 + l4 * 4 + r;
        const float t = acc[mi][ni][r] + bv;
        if (EPI == 0) {
          ((bf16_t*)out0)[(size_t)m * N + n] = __float2bfloat16(fmaxf(t, 0.f));
        } else {
          ((float*)out0)[(size_t)m * N + n] = rcp(1.f + ex2(-t * LOG2E));
        }
      }
    }
  }
}

// ---------------------------------------------------------------------------
// MEGA cooperative kernel: prep -> GEMM1 -> abstick -> GEMM4 with grid.sync
// between phases (replaces 3 kernel-launch boundaries; grid 256 x 512,
// LDS 128KB -> exactly 1 block/CU x 256 CUs co-resident; grid.sync's
// device-scope fence gives cross-XCD visibility of h/h2 per G16).
// ---------------------------------------------------------------------------
__global__ __launch_bounds__(512, 1)
void mega_kernel(const float* __restrict__ x, const float* __restrict__ u,
                 const float* __restrict__ W1, const float* __restrict__ b1,
                 const float* __restrict__ Wa, const float* __restrict__ ba,
                 const float* __restrict__ Wb, const float* __restrict__ bb,
                 const float* __restrict__ W2, const float* __restrict__ b2,
                 const float* __restrict__ W3, const float* __restrict__ b3,
                 float* __restrict__ recon, float* __restrict__ oalpha,
                 float* __restrict__ obeta, bf16_t* __restrict__ h,
                 bf16_t* __restrict__ h2, bf16_t* __restrict__ w1,
                 bf16_t* __restrict__ w3, bf16_t* __restrict__ wab,
                 bf16_t* __restrict__ w2p, float* __restrict__ bab)
{
  cg::grid_group grid = cg::this_grid();
  __shared__ char lds[131072];                 // max phase (GEMM4: 2x64KB)
  const int tid = threadIdx.x;

  // ---- phase 0: prep (grid-stride over weights) ---------------------------
  {
    const int W1U  = (HID * NDIM) / 4;
    const int W3U  = (NDIM * HID) / 4;
    const int WABN = 128 * HID;
    const int W2PN = HID * 64;
    const int TOT  = W1U + W3U + WABN + W2PN + 128;
    for (int i = blockIdx.x * blockDim.x + tid; i < TOT;
         i += gridDim.x * blockDim.x) {
      int j = i;
      if (j < W1U) {
        const f32x4 v = ((const f32x4*)W1)[j];
        u16x4 o; o[0]=f2b_u(v[0]); o[1]=f2b_u(v[1]); o[2]=f2b_u(v[2]); o[3]=f2b_u(v[3]);
        ((u16x4*)w1)[j] = o; continue;
      }
      j -= W1U;
      if (j < W3U) {
        const f32x4 v = ((const f32x4*)W3)[j];
        u16x4 o; o[0]=f2b_u(v[0]); o[1]=f2b_u(v[1]); o[2]=f2b_u(v[2]); o[3]=f2b_u(v[3]);
        ((u16x4*)w3)[j] = o; continue;
      }
      j -= W3U;
      if (j < WABN) {
        const int n = j >> 9, k = j & 511;
        float v = (n < 50) ? Wa[n * 512 + k] : ((n < 100) ? Wb[(n - 50) * 512 + k] : 0.f);
        wab[j] = __float2bfloat16(v); continue;
      }
      j -= WABN;
      if (j < W2PN) {
        const int n = j >> 6, k = j & 63;
        w2p[j] = __float2bfloat16(k < 50 ? W2[n * 50 + k] : 0.f); continue;
      }
      j -= W2PN;
      bab[j] = (j < 50) ? ba[j] : ((j < 100) ? bb[j - 50] : 0.f);
    }
  }
  grid.sync();

  // ---- phase 1: h = relu(x @ W1^T + b1)  (BM=128, A=f32) ------------------
  gemm_phase<1, 0, 128>(x, w1, b1, (void*)h, HID, NDIM, lds, tid);
  grid.sync();

  // ---- phase 2: alpha/beta + stick + GEMM3 -> h2 --------------------------
  {
    constexpr int BUF = 64 * 128 + 16384;      // 24576
    constexpr int PIL = 65536;
    constexpr int SMO = 73728;
    const bf16_t* A = h;
    const int swzid = ((blockIdx.x & 7) * (gridDim.x >> 3)) + (blockIdx.x >> 3);
    const int bm   = swzid;
    const int wid  = tid >> 6;
    const int lane = tid & 63;
    const int l15  = lane & 15;
    const int l4   = lane >> 4;
    const int wm   = (wid >> 2) * 32;
    const int wn   = (wid & 3) * 32;
    const int uw   = __builtin_amdgcn_readfirstlane(wid);
    const int K    = HID;

    f32x4 acc[2][2] = {};

    auto stage_AB = [&](char* buf, int k0) {
      {
        const int c  = tid;
        const int r  = c >> 3;
        const int sp = c & 7;
        const int sl = sp ^ (r & 7);
        gload16(A + (size_t)(bm * 64 + r) * K + k0 + sl * 8, buf + uw * 1024);
      }
      char* lB = buf + 8192;
      #pragma unroll
      for (int i = 0; i < 2; ++i) {
        const int c  = (i * 8 + uw) * 64 + lane;
        const int r  = c >> 3;
        const int sp = c & 7;
        const int sl = sp ^ (r & 7);
        gload16(wab + (size_t)r * K + k0 + sl * 8, lB + (i * 8 + uw) * 1024);
      }
    };
    auto compute1 = [&](const char* buf) {
      const char* lA = buf;
      const char* lB = buf + 8192;
      #pragma unroll
      for (int hh = 0; hh < 2; ++hh) {
        bf16x8 af[2], bfr[2];
        #pragma unroll
        for (int mi = 0; mi < 2; ++mi) {
          const int row = wm + mi * 16 + l15;
          const int sp  = (hh * 4 + l4) ^ (row & 7);
          af[mi] = *(const bf16x8*)(lA + row * 128 + sp * 16);
        }
        #pragma unroll
        for (int ni = 0; ni < 2; ++ni) {
          const int row = wn + ni * 16 + l15;
          const int sp  = (hh * 4 + l4) ^ (row & 7);
          bfr[ni] = *(const bf16x8*)(lB + row * 128 + sp * 16);
        }
        #pragma unroll
        for (int mi = 0; mi < 2; ++mi)
          #pragma unroll
          for (int ni = 0; ni < 2; ++ni)
            acc[mi][ni] = __builtin_amdgcn_mfma_f32_16x16x32_bf16(
                af[mi], bfr[ni], acc[mi][ni], 0, 0, 0);
      }
    };

    stage_AB(lds, 0);
    stage_AB(lds + BUF, 64);
    for (int t = 0; t < 8; ++t) {
      if (t + 1 < 8) WAIT_VMCNT(3);
      else           WAIT_VMCNT(0);
      __builtin_amdgcn_s_barrier();
      compute1(lds + (t & 1) * BUF);
      __builtin_amdgcn_s_barrier();
      __builtin_amdgcn_sched_barrier(0);
      if (t + 2 < 8) stage_AB(lds + (t & 1) * BUF, (t + 2) << 6);
    }

    const int ul = (lane < 49) ? lane : 0;
    float ureg[8];
    #pragma unroll
    for (int rr = 0; rr < 8; ++rr) {
      const size_t m = (size_t)(bm * 64 + wid * 8 + rr);
      ureg[rr] = u[m * 50 + ul];
    }

    #pragma unroll
    for (int i = 0; i < 8; ++i) {
      const int c  = (i * 8 + uw) * 64 + lane;
      const int r  = c >> 3;
      const int sp = c & 7;
      const int sl = sp ^ (r & 7);
      gload16(w2p + (size_t)r * 64 + sl * 8, lds + (i * 8 + uw) * 1024);
    }

    float* sm = (float*)(lds + SMO);
    #pragma unroll
    for (int ni = 0; ni < 2; ++ni) {
      const int n  = wn + ni * 16 + l15;
      const float bv = bab[n];
      #pragma unroll
      for (int mi = 0; mi < 2; ++mi) {
        #pragma unroll
        for (int r = 0; r < 4; ++r) {
          const int ml = wm + mi * 16 + l4 * 4 + r;
          const int m  = bm * 64 + ml;
          const float t = acc[mi][ni][r] + bv;
          if (n < 100) {
            const float y =
                (t > 20.f ? t : lg2(1.f + ex2(t * LOG2E)) * RLOG2E) + 1e-4f;
            if (n < 50) oalpha[(size_t)m * 50 + n] = y;
            else        obeta[(size_t)m * 50 + (n - 50)] = y;
            sm[ml * 104 + n + (n < 50 ? 0 : 2)] = y;
          }
        }
      }
    }
    __syncthreads();

    #pragma unroll 1
    for (int rr = 0; rr < 8; ++rr) {
      const int rl = wid * 8 + rr;
      float v = 1.f, t = 1.f;
      if (lane < 49) {
        const float a  = sm[rl * 104 + lane];
        const float b  = sm[rl * 104 + 52 + lane];
        const float uu = ureg[rr];
        const float tb = ex2(lg2(uu) * rcp(b));
        v = ex2(lg2(1.f - tb) * rcp(a));
        t = 1.f - v;
      }
      float p = t;
      #pragma unroll
      for (int d = 1; d < 64; d <<= 1) {
        const float o = __shfl_up(p, d, 64);
        if (lane >= d) p *= o;
      }
      float e = __shfl_up(p, 1, 64);
      if (lane == 0) e = 1.f;
      const float piv = (lane < 50) ? v * e : 0.f;
      *(unsigned short*)(lds + PIL + rl * 128 +
                         (((lane >> 3) ^ (rl & 7)) << 4) + ((lane & 7) << 1)) =
          f2b_u(piv);
    }
    __syncthreads();

    const int wn3 = (wid & 3) * 128;
    f32x4 acc3[2][8] = {};
    #pragma unroll
    for (int hh = 0; hh < 2; ++hh) {
      bf16x8 af[2], bfr[8];
      #pragma unroll
      for (int mi = 0; mi < 2; ++mi) {
        const int row = wm + mi * 16 + l15;
        const int sp  = (hh * 4 + l4) ^ (row & 7);
        af[mi] = *(const bf16x8*)(lds + PIL + row * 128 + sp * 16);
      }
      #pragma unroll
      for (int ni = 0; ni < 8; ++ni) {
        const int row = wn3 + ni * 16 + l15;
        const int sp  = (hh * 4 + l4) ^ (row & 7);
        bfr[ni] = *(const bf16x8*)(lds + row * 128 + sp * 16);
      }
      #pragma unroll
      for (int mi = 0; mi < 2; ++mi)
        #pragma unroll
        for (int ni = 0; ni < 8; ++ni)
          acc3[mi][ni] = __builtin_amdgcn_mfma_f32_16x16x32_bf16(
              af[mi], bfr[ni], acc3[mi][ni], 0, 0, 0);
    }
    #pragma unroll
    for (int ni = 0; ni < 8; ++ni) {
      const int n  = wn3 + ni * 16 + l15;
      const float bv = b2[n];
      #pragma unroll
      for (int mi = 0; mi < 2; ++mi) {
        #pragma unroll
        for (int r = 0; r < 4; ++r) {
          const int m  = bm * 64 + wm + mi * 16 + l4 * 4 + r;
          h2[(size_t)m * HID + n] =
              __float2bfloat16(fmaxf(acc3[mi][ni][r] + bv, 0.f));
        }
      }
    }
  }
  grid.sync();

  // ---- phase 3: recon = sigmoid(h2 @ W3^T + b3)  (BM=256) -----------------
  gemm_phase<0, 1, 256>(h2, w3, b3, (void*)recon, NDIM, HID, lds, tid);
}

// ---------------------------------------------------------------------------
extern "C" void kernel_launch(void* const* d_in, const int* in_sizes, int n_in,
                              void* d_out, int out_size, void* d_ws, size_t ws_size,
                              hipStream_t stream)
{
  const float* x  = (const float*)d_in[0];
  const float* u  = (const float*)d_in[1];
  const float* W1 = (const float*)d_in[2];
  const float* b1 = (const float*)d_in[3];
  const float* Wa = (const float*)d_in[4];
  const float* ba = (const float*)d_in[5];
  const float* Wb = (const float*)d_in[6];
  const float* bb = (const float*)d_in[7];
  const float* W2 = (const float*)d_in[8];
  const float* b2 = (const float*)d_in[9];
  const float* W3 = (const float*)d_in[10];
  const float* b3 = (const float*)d_in[11];

  float* recon  = (float*)d_out;
  float* oalpha = recon + (size_t)BATCH * NDIM;
  float* obeta  = oalpha + (size_t)BATCH * LAT;

  char* ws = (char*)d_ws;
  bf16_t* h2  = (bf16_t*)(ws);                 // 16,777,216
  bf16_t* h   = (bf16_t*)(ws + 16777216);      // 16,777,216
  bf16_t* w1  = (bf16_t*)(ws + 33554432);      //  1,048,576
  bf16_t* w3  = (bf16_t*)(ws + 34603008);      //  1,048,576
  bf16_t* wab = (bf16_t*)(ws + 35651584);      //    131,072
  bf16_t* w2p = (bf16_t*)(ws + 35782656);      //     65,536
  float*  bab = (float*)(ws + 35848192);       //        512

  void* kargs[] = {
      (void*)&x,  (void*)&u,  (void*)&W1, (void*)&b1, (void*)&Wa, (void*)&ba,
      (void*)&Wb, (void*)&bb, (void*)&W2, (void*)&b2, (void*)&W3, (void*)&b3,
      (void*)&recon, (void*)&oalpha, (void*)&obeta, (void*)&h, (void*)&h2,
      (void*)&w1, (void*)&w3, (void*)&wab, (void*)&w2p, (void*)&bab};
  hipLaunchCooperativeKernel((const void*)mega_kernel, dim3(256), dim3(512),
                             kargs, 0, stream);
}

// Round 25
// 178.995 us; speedup vs baseline: 1.0097x; 1.0034x over previous
//
#include <hip/hip_runtime.h>
#include <hip/hip_bf16.h>
#include <hip/hip_cooperative_groups.h>

namespace cg = cooperative_groups;

typedef __hip_bfloat16 bf16_t;
typedef __attribute__((ext_vector_type(4))) float f32x4;
typedef __attribute__((ext_vector_type(8))) __bf16 bf16x8;
typedef __attribute__((ext_vector_type(8))) short s16x8;
typedef __attribute__((ext_vector_type(4))) unsigned short u16x4;

#define BATCH 16384
#define NDIM  1024
#define HID   512
#define LAT   50

#define LOG2E 1.44269504088896340736f
#define RLOG2E 0.69314718055994530942f

__device__ __forceinline__ float ex2(float x) { return __builtin_amdgcn_exp2f(x); }
__device__ __forceinline__ float lg2(float x) { return __builtin_amdgcn_logf(x); }
__device__ __forceinline__ float rcp(float x) { return __builtin_amdgcn_rcpf(x); }

__device__ inline unsigned short f2b_u(float f) {
  union { bf16_t b; unsigned short u; } cv; cv.b = __float2bfloat16(f); return cv.u;
}

__device__ __forceinline__ void gload16(const void* src, void* dst_lds) {
  __builtin_amdgcn_global_load_lds(
      reinterpret_cast<const __attribute__((address_space(1))) void*>(
          reinterpret_cast<unsigned long long>(src)),
      reinterpret_cast<__attribute__((address_space(3))) void*>(
          static_cast<unsigned>(reinterpret_cast<unsigned long long>(dst_lds))),
      16, 0, 0);
}

#define WAIT_VMCNT(N)                                          \
  do {                                                         \
    asm volatile("s_waitcnt vmcnt(%0)" ::"i"(N) : "memory");   \
    __builtin_amdgcn_sched_barrier(0);                         \
  } while (0)
#define WAIT_LGKM0                                             \
  do {                                                         \
    asm volatile("s_waitcnt lgkmcnt(0)" ::: "memory");         \
    __builtin_amdgcn_sched_barrier(0);                         \
  } while (0)

// ---------------------------------------------------------------------------
// GEMM phase (R19 best-measured structure, verbatim): C = epi(A@B^T + bias).
// Tile BM x 256, BK=64, 8 waves (2M x 4N); front-loaded staging, one
// vmcnt(0)+barrier per K-tile; setprio around MFMA clusters.
// ---------------------------------------------------------------------------
template<int A_F32, int EPI, int BM>
__device__ __forceinline__
void gemm_phase(const void* __restrict__ Av, const bf16_t* __restrict__ B,
                const float* __restrict__ bias, void* __restrict__ out0,
                int N, int K, char* lds, int tid)
{
  constexpr int BN  = 256;
  constexpr int BUF = (BM + BN) * 128;        // 48KB / 64KB
  constexpr int RA  = BM / 64;
  constexpr int MI  = BM / 32;
  constexpr int FPQ = MI / 4;

  const int swzid = ((blockIdx.x & 7) * (gridDim.x >> 3)) + (blockIdx.x >> 3);
  const int nblocks = N / BN;
  const int bn   = swzid % nblocks;
  const int bm   = swzid / nblocks;
  const int wid  = tid >> 6;
  const int lane = tid & 63;
  const int l15  = lane & 15;
  const int l4   = lane >> 4;
  const int wm   = (wid >> 2) * (BM / 2);
  const int wn   = (wid & 3) * 64;
  const int uw   = __builtin_amdgcn_readfirstlane(wid);

  f32x4 acc[MI][4] = {};
  f32x4 areg[4];

  auto stage_A_round = [&](char* buf, int k0, int i) {
    const bf16_t* A = (const bf16_t*)Av;
    const int c  = (i * 8 + uw) * 64 + lane;
    const int r  = c >> 3;
    const int sp = c & 7;
    const int sl = sp ^ (r & 7);
    gload16(A + (size_t)(bm * BM + r) * K + k0 + sl * 8,
            buf + (i * 8 + uw) * 1024);
  };
  auto stage_B_round = [&](char* buf, int k0, int i) {
    char* lB = buf + BM * 128;
    const int c  = (i * 8 + uw) * 64 + lane;
    const int r  = c >> 3;
    const int sp = c & 7;
    const int sl = sp ^ (r & 7);
    gload16(B + (size_t)(bn * BN + r) * K + k0 + sl * 8,
            lB + (i * 8 + uw) * 1024);
  };
  auto load_A_f32 = [&](int k0) {
    const float* A = (const float*)Av;
    #pragma unroll
    for (int j = 0; j < 2; ++j) {
      const int c  = j * 512 + tid;
      const int r  = c >> 3;
      const int sl = c & 7;
      const float* s = A + (size_t)(bm * BM + r) * K + k0 + sl * 8;
      areg[2 * j]     = *(const f32x4*)s;
      areg[2 * j + 1] = *(const f32x4*)(s + 4);
    }
  };
  auto write_A_f32 = [&](char* buf) {
    #pragma unroll
    for (int j = 0; j < 2; ++j) {
      const int c  = j * 512 + tid;
      const int r  = c >> 3;
      const int sl = c & 7;
      const int sp = sl ^ (r & 7);
      union { s16x8 v; unsigned short us[8]; } o;
      const f32x4 v0 = areg[2 * j], v1 = areg[2 * j + 1];
      o.us[0]=f2b_u(v0[0]); o.us[1]=f2b_u(v0[1]); o.us[2]=f2b_u(v0[2]); o.us[3]=f2b_u(v0[3]);
      o.us[4]=f2b_u(v1[0]); o.us[5]=f2b_u(v1[1]); o.us[6]=f2b_u(v1[2]); o.us[7]=f2b_u(v1[3]);
      *(s16x8*)(buf + r * 128 + sp * 16) = o.v;
    }
  };

  const int nt = K >> 6;
  if constexpr (A_F32) {
    load_A_f32(0); write_A_f32(lds);
  } else {
    #pragma unroll
    for (int i = 0; i < RA; ++i) stage_A_round(lds, 0, i);
  }
  #pragma unroll
  for (int i = 0; i < 4; ++i) stage_B_round(lds, 0, i);
  WAIT_VMCNT(0);
  if (A_F32) WAIT_LGKM0;
  __builtin_amdgcn_s_barrier();

  for (int t = 0; t < nt; ++t) {
    char* buf  = lds + (t & 1) * BUF;
    char* nbuf = lds + ((t + 1) & 1) * BUF;
    const char* lA = buf;
    const char* lB = buf + BM * 128;
    const bool pf  = (t + 1 < nt);
    const int k0n  = (t + 1) << 6;

    if (pf) {
      if constexpr (A_F32) {
        load_A_f32(k0n);
      } else {
        #pragma unroll
        for (int i = 0; i < RA; ++i) stage_A_round(nbuf, k0n, i);
      }
      #pragma unroll
      for (int i = 0; i < 4; ++i) stage_B_round(nbuf, k0n, i);
    }

    bf16x8 bfr[4][2];
    #pragma unroll
    for (int ni = 0; ni < 4; ++ni)
      #pragma unroll
      for (int h = 0; h < 2; ++h) {
        const int row = wn + ni * 16 + l15;
        const int sp  = (h * 4 + l4) ^ (row & 7);
        bfr[ni][h] = *(const bf16x8*)(lB + row * 128 + sp * 16);
      }

    #pragma unroll
    for (int q = 0; q < 4; ++q) {
      bf16x8 af[FPQ][2];
      #pragma unroll
      for (int f = 0; f < FPQ; ++f)
        #pragma unroll
        for (int h = 0; h < 2; ++h) {
          const int row = wm + (q * FPQ + f) * 16 + l15;
          const int sp  = (h * 4 + l4) ^ (row & 7);
          af[f][h] = *(const bf16x8*)(lA + row * 128 + sp * 16);
        }
      __builtin_amdgcn_s_setprio(1);
      #pragma unroll
      for (int f = 0; f < FPQ; ++f)
        #pragma unroll
        for (int ni = 0; ni < 4; ++ni)
          #pragma unroll
          for (int h = 0; h < 2; ++h)
            acc[q * FPQ + f][ni] = __builtin_amdgcn_mfma_f32_16x16x32_bf16(
                af[f][h], bfr[ni][h], acc[q * FPQ + f][ni], 0, 0, 0);
      __builtin_amdgcn_s_setprio(0);
    }

    if (A_F32 && pf) write_A_f32(nbuf);
    WAIT_VMCNT(0);
    if (A_F32) WAIT_LGKM0;
    __builtin_amdgcn_s_barrier();
  }

  #pragma unroll
  for (int ni = 0; ni < 4; ++ni) {
    const int n  = bn * BN + wn + ni * 16 + l15;
    const float bv = bias[n];
    #pragma unroll
    for (int mi = 0; mi < MI; ++mi) {
      #pragma unroll
      for (int r = 0; r < 4; ++r) {
        const int m  = bm * BM + wm + mi * 16 + l4 * 4 + r;
        const float t = acc[mi][ni][r] + bv;
        if (EPI == 0) {
          ((bf16_t*)out0)[(size_t)m * N + n] = __float2bfloat16(fmaxf(t, 0.f));
        } else {
          ((float*)out0)[(size_t)m * N + n] = rcp(1.f + ex2(-t * LOG2E));
        }
      }
    }
  }
}

// ---------------------------------------------------------------------------
// MEGA cooperative kernel: prep -> GEMM1 -> abstick -> GEMM4 with grid.sync
// between phases (replaces 3 kernel-launch boundaries; grid 256 x 512,
// LDS 128KB -> exactly 1 block/CU x 256 CUs co-resident; grid.sync's
// device-scope fence gives cross-XCD visibility of h/h2 per G16).
// ---------------------------------------------------------------------------
__global__ __launch_bounds__(512, 1)
void mega_kernel(const float* __restrict__ x, const float* __restrict__ u,
                 const float* __restrict__ W1, const float* __restrict__ b1,
                 const float* __restrict__ Wa, const float* __restrict__ ba,
                 const float* __restrict__ Wb, const float* __restrict__ bb,
                 const float* __restrict__ W2, const float* __restrict__ b2,
                 const float* __restrict__ W3, const float* __restrict__ b3,
                 float* __restrict__ recon, float* __restrict__ oalpha,
                 float* __restrict__ obeta, bf16_t* __restrict__ h,
                 bf16_t* __restrict__ h2, bf16_t* __restrict__ w1,
                 bf16_t* __restrict__ w3, bf16_t* __restrict__ wab,
                 bf16_t* __restrict__ w2p, float* __restrict__ bab)
{
  cg::grid_group grid = cg::this_grid();
  __shared__ char lds[131072];                 // max phase (GEMM4: 2x64KB)
  const int tid = threadIdx.x;

  // ---- phase 0: prep (grid-stride over weights) ---------------------------
  {
    const int W1U  = (HID * NDIM) / 4;
    const int W3U  = (NDIM * HID) / 4;
    const int WABN = 128 * HID;
    const int W2PN = HID * 64;
    const int TOT  = W1U + W3U + WABN + W2PN + 128;
    for (int i = blockIdx.x * blockDim.x + tid; i < TOT;
         i += gridDim.x * blockDim.x) {
      int j = i;
      if (j < W1U) {
        const f32x4 v = ((const f32x4*)W1)[j];
        u16x4 o; o[0]=f2b_u(v[0]); o[1]=f2b_u(v[1]); o[2]=f2b_u(v[2]); o[3]=f2b_u(v[3]);
        ((u16x4*)w1)[j] = o; continue;
      }
      j -= W1U;
      if (j < W3U) {
        const f32x4 v = ((const f32x4*)W3)[j];
        u16x4 o; o[0]=f2b_u(v[0]); o[1]=f2b_u(v[1]); o[2]=f2b_u(v[2]); o[3]=f2b_u(v[3]);
        ((u16x4*)w3)[j] = o; continue;
      }
      j -= W3U;
      if (j < WABN) {
        const int n = j >> 9, k = j & 511;
        float v = (n < 50) ? Wa[n * 512 + k] : ((n < 100) ? Wb[(n - 50) * 512 + k] : 0.f);
        wab[j] = __float2bfloat16(v); continue;
      }
      j -= WABN;
      if (j < W2PN) {
        const int n = j >> 6, k = j & 63;
        w2p[j] = __float2bfloat16(k < 50 ? W2[n * 50 + k] : 0.f); continue;
      }
      j -= W2PN;
      bab[j] = (j < 50) ? ba[j] : ((j < 100) ? bb[j - 50] : 0.f);
    }
  }
  grid.sync();

  // ---- phase 1: h = relu(x @ W1^T + b1)  (BM=128, A=f32) ------------------
  gemm_phase<1, 0, 128>(x, w1, b1, (void*)h, HID, NDIM, lds, tid);
  grid.sync();

  // ---- phase 2: alpha/beta + stick + GEMM3 -> h2 --------------------------
  {
    constexpr int BUF = 64 * 128 + 16384;      // 24576
    constexpr int PIL = 65536;
    constexpr int SMO = 73728;
    const bf16_t* A = h;
    const int swzid = ((blockIdx.x & 7) * (gridDim.x >> 3)) + (blockIdx.x >> 3);
    const int bm   = swzid;
    const int wid  = tid >> 6;
    const int lane = tid & 63;
    const int l15  = lane & 15;
    const int l4   = lane >> 4;
    const int wm   = (wid >> 2) * 32;
    const int wn   = (wid & 3) * 32;
    const int uw   = __builtin_amdgcn_readfirstlane(wid);
    const int K    = HID;

    f32x4 acc[2][2] = {};

    auto stage_AB = [&](char* buf, int k0) {
      {
        const int c  = tid;
        const int r  = c >> 3;
        const int sp = c & 7;
        const int sl = sp ^ (r & 7);
        gload16(A + (size_t)(bm * 64 + r) * K + k0 + sl * 8, buf + uw * 1024);
      }
      char* lB = buf + 8192;
      #pragma unroll
      for (int i = 0; i < 2; ++i) {
        const int c  = (i * 8 + uw) * 64 + lane;
        const int r  = c >> 3;
        const int sp = c & 7;
        const int sl = sp ^ (r & 7);
        gload16(wab + (size_t)r * K + k0 + sl * 8, lB + (i * 8 + uw) * 1024);
      }
    };
    auto compute1 = [&](const char* buf) {
      const char* lA = buf;
      const char* lB = buf + 8192;
      #pragma unroll
      for (int hh = 0; hh < 2; ++hh) {
        bf16x8 af[2], bfr[2];
        #pragma unroll
        for (int mi = 0; mi < 2; ++mi) {
          const int row = wm + mi * 16 + l15;
          const int sp  = (hh * 4 + l4) ^ (row & 7);
          af[mi] = *(const bf16x8*)(lA + row * 128 + sp * 16);
        }
        #pragma unroll
        for (int ni = 0; ni < 2; ++ni) {
          const int row = wn + ni * 16 + l15;
          const int sp  = (hh * 4 + l4) ^ (row & 7);
          bfr[ni] = *(const bf16x8*)(lB + row * 128 + sp * 16);
        }
        #pragma unroll
        for (int mi = 0; mi < 2; ++mi)
          #pragma unroll
          for (int ni = 0; ni < 2; ++ni)
            acc[mi][ni] = __builtin_amdgcn_mfma_f32_16x16x32_bf16(
                af[mi], bfr[ni], acc[mi][ni], 0, 0, 0);
      }
    };

    stage_AB(lds, 0);
    stage_AB(lds + BUF, 64);
    for (int t = 0; t < 8; ++t) {
      if (t + 1 < 8) WAIT_VMCNT(3);
      else           WAIT_VMCNT(0);
      __builtin_amdgcn_s_barrier();
      compute1(lds + (t & 1) * BUF);
      __builtin_amdgcn_s_barrier();
      __builtin_amdgcn_sched_barrier(0);
      if (t + 2 < 8) stage_AB(lds + (t & 1) * BUF, (t + 2) << 6);
    }

    const int ul = (lane < 49) ? lane : 0;
    float ureg[8];
    #pragma unroll
    for (int rr = 0; rr < 8; ++rr) {
      const size_t m = (size_t)(bm * 64 + wid * 8 + rr);
      ureg[rr] = u[m * 50 + ul];
    }

    #pragma unroll
    for (int i = 0; i < 8; ++i) {
      const int c  = (i * 8 + uw) * 64 + lane;
      const int r  = c >> 3;
      const int sp = c & 7;
      const int sl = sp ^ (r & 7);
      gload16(w2p + (size_t)r * 64 + sl * 8, lds + (i * 8 + uw) * 1024);
    }

    float* sm = (float*)(lds + SMO);
    #pragma unroll
    for (int ni = 0; ni < 2; ++ni) {
      const int n  = wn + ni * 16 + l15;
      const float bv = bab[n];
      #pragma unroll
      for (int mi = 0; mi < 2; ++mi) {
        #pragma unroll
        for (int r = 0; r < 4; ++r) {
          const int ml = wm + mi * 16 + l4 * 4 + r;
          const int m  = bm * 64 + ml;
          const float t = acc[mi][ni][r] + bv;
          if (n < 100) {
            const float y =
                (t > 20.f ? t : lg2(1.f + ex2(t * LOG2E)) * RLOG2E) + 1e-4f;
            if (n < 50) oalpha[(size_t)m * 50 + n] = y;
            else        obeta[(size_t)m * 50 + (n - 50)] = y;
            sm[ml * 104 + n + (n < 50 ? 0 : 2)] = y;
          }
        }
      }
    }
    __syncthreads();

    #pragma unroll 1
    for (int rr = 0; rr < 8; ++rr) {
      const int rl = wid * 8 + rr;
      float v = 1.f, t = 1.f;
      if (lane < 49) {
        const float a  = sm[rl * 104 + lane];
        const float b  = sm[rl * 104 + 52 + lane];
        const float uu = ureg[rr];
        const float tb = ex2(lg2(uu) * rcp(b));
        v = ex2(lg2(1.f - tb) * rcp(a));
        t = 1.f - v;
      }
      float p = t;
      #pragma unroll
      for (int d = 1; d < 64; d <<= 1) {
        const float o = __shfl_up(p, d, 64);
        if (lane >= d) p *= o;
      }
      float e = __shfl_up(p, 1, 64);
      if (lane == 0) e = 1.f;
      const float piv = (lane < 50) ? v * e : 0.f;
      *(unsigned short*)(lds + PIL + rl * 128 +
                         (((lane >> 3) ^ (rl & 7)) << 4) + ((lane & 7) << 1)) =
          f2b_u(piv);
    }
    __syncthreads();

    const int wn3 = (wid & 3) * 128;
    f32x4 acc3[2][8] = {};
    #pragma unroll
    for (int hh = 0; hh < 2; ++hh) {
      bf16x8 af[2], bfr[8];
      #pragma unroll
      for (int mi = 0; mi < 2; ++mi) {
        const int row = wm + mi * 16 + l15;
        const int sp  = (hh * 4 + l4) ^ (row & 7);
        af[mi] = *(const bf16x8*)(lds + PIL + row * 128 + sp * 16);
      }
      #pragma unroll
      for (int ni = 0; ni < 8; ++ni) {
        const int row = wn3 + ni * 16 + l15;
        const int sp  = (hh * 4 + l4) ^ (row & 7);
        bfr[ni] = *(const bf16x8*)(lds + row * 128 + sp * 16);
      }
      #pragma unroll
      for (int mi = 0; mi < 2; ++mi)
        #pragma unroll
        for (int ni = 0; ni < 8; ++ni)
          acc3[mi][ni] = __builtin_amdgcn_mfma_f32_16x16x32_bf16(
              af[mi], bfr[ni], acc3[mi][ni], 0, 0, 0);
    }
    #pragma unroll
    for (int ni = 0; ni < 8; ++ni) {
      const int n  = wn3 + ni * 16 + l15;
      const float bv = b2[n];
      #pragma unroll
      for (int mi = 0; mi < 2; ++mi) {
        #pragma unroll
        for (int r = 0; r < 4; ++r) {
          const int m  = bm * 64 + wm + mi * 16 + l4 * 4 + r;
          h2[(size_t)m * HID + n] =
              __float2bfloat16(fmaxf(acc3[mi][ni][r] + bv, 0.f));
        }
      }
    }
  }
  grid.sync();

  // ---- phase 3: recon = sigmoid(h2 @ W3^T + b3)  (BM=256) -----------------
  gemm_phase<0, 1, 256>(h2, w3, b3, (void*)recon, NDIM, HID, lds, tid);
}

// ---------------------------------------------------------------------------
extern "C" void kernel_launch(void* const* d_in, const int* in_sizes, int n_in,
                              void* d_out, int out_size, void* d_ws, size_t ws_size,
                              hipStream_t stream)
{
  const float* x  = (const float*)d_in[0];
  const float* u  = (const float*)d_in[1];
  const float* W1 = (const float*)d_in[2];
  const float* b1 = (const float*)d_in[3];
  const float* Wa = (const float*)d_in[4];
  const float* ba = (const float*)d_in[5];
  const float* Wb = (const float*)d_in[6];
  const float* bb = (const float*)d_in[7];
  const float* W2 = (const float*)d_in[8];
  const float* b2 = (const float*)d_in[9];
  const float* W3 = (const float*)d_in[10];
  const float* b3 = (const float*)d_in[11];

  float* recon  = (float*)d_out;
  float* oalpha = recon + (size_t)BATCH * NDIM;
  float* obeta  = oalpha + (size_t)BATCH * LAT;

  char* ws = (char*)d_ws;
  bf16_t* h2  = (bf16_t*)(ws);                 // 16,777,216
  bf16_t* h   = (bf16_t*)(ws + 16777216);      // 16,777,216
  bf16_t* w1  = (bf16_t*)(ws + 33554432);      //  1,048,576
  bf16_t* w3  = (bf16_t*)(ws + 34603008);      //  1,048,576
  bf16_t* wab = (bf16_t*)(ws + 35651584);      //    131,072
  bf16_t* w2p = (bf16_t*)(ws + 35782656);      //     65,536
  float*  bab = (float*)(ws + 35848192);       //        512

  void* kargs[] = {
      (void*)&x,  (void*)&u,  (void*)&W1, (void*)&b1, (void*)&Wa, (void*)&ba,
      (void*)&Wb, (void*)&bb, (void*)&W2, (void*)&b2, (void*)&W3, (void*)&b3,
      (void*)&recon, (void*)&oalpha, (void*)&obeta, (void*)&h, (void*)&h2,
      (void*)&w1, (void*)&w3, (void*)&wab, (void*)&w2p, (void*)&bab};
  hipLaunchCooperativeKernel((const void*)mega_kernel, dim3(256), dim3(512),
                             kargs, 0, stream);
}

// Round 26
// 77.309 us; speedup vs baseline: 2.3378x; 2.3153x over previous
//
#include <hip/hip_runtime.h>
#include <hip/hip_bf16.h>

typedef __hip_bfloat16 bf16_t;
typedef __attribute__((ext_vector_type(4))) float f32x4;
typedef __attribute__((ext_vector_type(8))) __bf16 bf16x8;
typedef __attribute__((ext_vector_type(8))) short s16x8;
typedef __attribute__((ext_vector_type(4))) unsigned short u16x4;

#define BATCH 16384
#define NDIM  1024
#define HID   512
#define LAT   50

#define LOG2E 1.44269504088896340736f
#define RLOG2E 0.69314718055994530942f

__device__ __forceinline__ float ex2(float x) { return __builtin_amdgcn_exp2f(x); }
__device__ __forceinline__ float lg2(float x) { return __builtin_amdgcn_logf(x); }
__device__ __forceinline__ float rcp(float x) { return __builtin_amdgcn_rcpf(x); }

__device__ inline unsigned short f2b_u(float f) {
  union { bf16_t b; unsigned short u; } cv; cv.b = __float2bfloat16(f); return cv.u;
}

__device__ __forceinline__ void gload16(const void* src, void* dst_lds) {
  __builtin_amdgcn_global_load_lds(
      reinterpret_cast<const __attribute__((address_space(1))) void*>(
          reinterpret_cast<unsigned long long>(src)),
      reinterpret_cast<__attribute__((address_space(3))) void*>(
          static_cast<unsigned>(reinterpret_cast<unsigned long long>(dst_lds))),
      16, 0, 0);
}

// N must be a compile-time literal (asm "i" constraint).
#define WAIT_VMCNT(N)                                          \
  do {                                                         \
    asm volatile("s_waitcnt vmcnt(%0)" ::"i"(N) : "memory");   \
    __builtin_amdgcn_sched_barrier(0);                         \
  } while (0)
#define WAIT_LGKM0                                             \
  do {                                                         \
    asm volatile("s_waitcnt lgkmcnt(0)" ::: "memory");         \
    __builtin_amdgcn_sched_barrier(0);                         \
  } while (0)

// ---------------------------------------------------------------------------
// prep: WEIGHTS ONLY. w1[512][1024], w3[1024][512] bf16; wab [128][512];
// w2p [512][64]; bab[128].
// ---------------------------------------------------------------------------
__global__ void prep_w_kernel(const float* __restrict__ W1, const float* __restrict__ W3,
                              const float* __restrict__ Wa, const float* __restrict__ Wb,
                              const float* __restrict__ W2, const float* __restrict__ ba,
                              const float* __restrict__ bb,
                              bf16_t* __restrict__ w1, bf16_t* __restrict__ w3,
                              bf16_t* __restrict__ wab, bf16_t* __restrict__ w2p,
                              float* __restrict__ bab)
{
  const int W1U  = (HID * NDIM) / 4;
  const int W3U  = (NDIM * HID) / 4;
  const int WABN = 128 * HID;
  const int W2PN = HID * 64;
  const int TOT  = W1U + W3U + WABN + W2PN + 128;
  for (int i = blockIdx.x * blockDim.x + threadIdx.x; i < TOT;
       i += gridDim.x * blockDim.x) {
    int j = i;
    if (j < W1U) {
      const f32x4 v = ((const f32x4*)W1)[j];
      u16x4 o; o[0]=f2b_u(v[0]); o[1]=f2b_u(v[1]); o[2]=f2b_u(v[2]); o[3]=f2b_u(v[3]);
      ((u16x4*)w1)[j] = o; continue;
    }
    j -= W1U;
    if (j < W3U) {
      const f32x4 v = ((const f32x4*)W3)[j];
      u16x4 o; o[0]=f2b_u(v[0]); o[1]=f2b_u(v[1]); o[2]=f2b_u(v[2]); o[3]=f2b_u(v[3]);
      ((u16x4*)w3)[j] = o; continue;
    }
    j -= W3U;
    if (j < WABN) {
      const int n = j >> 9, k = j & 511;
      float v = (n < 50) ? Wa[n * 512 + k] : ((n < 100) ? Wb[(n - 50) * 512 + k] : 0.f);
      wab[j] = __float2bfloat16(v); continue;
    }
    j -= WABN;
    if (j < W2PN) {
      const int n = j >> 6, k = j & 63;
      w2p[j] = __float2bfloat16(k < 50 ? W2[n * 50 + k] : 0.f); continue;
    }
    j -= W2PN;
    bab[j] = (j < 50) ? ba[j] : ((j < 100) ? bb[j - 50] : 0.f);
  }
}

// ---------------------------------------------------------------------------
// BIG-TILE GEMM (R19/R21 best-measured config): front-loaded staging, one
// barrier per tile. BM=128: min-waves=2; BM=256: min-waves=1 (acc alone is
// 128 VGPR; a 128 cap forced spills).
// EPI: 0=relu->bf16, 1=sigmoid->f32.
// ---------------------------------------------------------------------------
template<int A_F32, int EPI, int BM>
__global__ __launch_bounds__(512, BM == 128 ? 2 : 1)
void gemm256_kernel(const void* __restrict__ Av, const bf16_t* __restrict__ B,
                    const float* __restrict__ bias, void* __restrict__ out0,
                    int M, int N, int K)
{
  constexpr int BN  = 256;
  constexpr int BUF = (BM + BN) * 128;        // 48KB / 64KB
  constexpr int RA  = BM / 64;                // A bf16 staging rounds
  constexpr int MI  = BM / 32;                // per-wave A frags
  constexpr int FPQ = MI / 4;                 // A frags per quadrant
  __shared__ char lds[2 * BUF];

  const int tid  = threadIdx.x;
  const int swzid = ((blockIdx.x & 7) * (gridDim.x >> 3)) + (blockIdx.x >> 3);
  const int nblocks = N / BN;
  const int bn   = swzid % nblocks;
  const int bm   = swzid / nblocks;
  const int wid  = tid >> 6;
  const int lane = tid & 63;
  const int l15  = lane & 15;
  const int l4   = lane >> 4;
  const int wm   = (wid >> 2) * (BM / 2);
  const int wn   = (wid & 3) * 64;
  const int uw   = __builtin_amdgcn_readfirstlane(wid);

  f32x4 acc[MI][4] = {};
  f32x4 areg[4];                               // A_F32 in-flight regs

  auto stage_A_round = [&](char* buf, int k0, int i) {
    const bf16_t* A = (const bf16_t*)Av;
    const int c  = (i * 8 + uw) * 64 + lane;
    const int r  = c >> 3;
    const int sp = c & 7;
    const int sl = sp ^ (r & 7);
    gload16(A + (size_t)(bm * BM + r) * K + k0 + sl * 8,
            buf + (i * 8 + uw) * 1024);
  };
  auto stage_B_round = [&](char* buf, int k0, int i) {
    char* lB = buf + BM * 128;
    const int c  = (i * 8 + uw) * 64 + lane;
    const int r  = c >> 3;
    const int sp = c & 7;
    const int sl = sp ^ (r & 7);
    gload16(B + (size_t)(bn * BN + r) * K + k0 + sl * 8,
            lB + (i * 8 + uw) * 1024);
  };
  auto load_A_f32 = [&](int k0) {              // BM=128: 1024 cells, 2/thread
    const float* A = (const float*)Av;
    #pragma unroll
    for (int j = 0; j < 2; ++j) {
      const int c  = j * 512 + tid;
      const int r  = c >> 3;
      const int sl = c & 7;
      const float* s = A + (size_t)(bm * BM + r) * K + k0 + sl * 8;
      areg[2 * j]     = *(const f32x4*)s;
      areg[2 * j + 1] = *(const f32x4*)(s + 4);
    }
  };
  auto write_A_f32 = [&](char* buf) {
    #pragma unroll
    for (int j = 0; j < 2; ++j) {
      const int c  = j * 512 + tid;
      const int r  = c >> 3;
      const int sl = c & 7;
      const int sp = sl ^ (r & 7);
      union { s16x8 v; unsigned short us[8]; } o;
      const f32x4 v0 = areg[2 * j], v1 = areg[2 * j + 1];
      o.us[0]=f2b_u(v0[0]); o.us[1]=f2b_u(v0[1]); o.us[2]=f2b_u(v0[2]); o.us[3]=f2b_u(v0[3]);
      o.us[4]=f2b_u(v1[0]); o.us[5]=f2b_u(v1[1]); o.us[6]=f2b_u(v1[2]); o.us[7]=f2b_u(v1[3]);
      *(s16x8*)(buf + r * 128 + sp * 16) = o.v;
    }
  };

  // ---- prologue: stage tile 0 ---------------------------------------------
  const int nt = K >> 6;
  if constexpr (A_F32) {
    load_A_f32(0); write_A_f32(lds);
  } else {
    #pragma unroll
    for (int i = 0; i < RA; ++i) stage_A_round(lds, 0, i);
  }
  #pragma unroll
  for (int i = 0; i < 4; ++i) stage_B_round(lds, 0, i);
  WAIT_VMCNT(0);
  if (A_F32) WAIT_LGKM0;
  __builtin_amdgcn_s_barrier();

  // ---- K-tile loop ---------------------------------------------------------
  for (int t = 0; t < nt; ++t) {
    char* buf  = lds + (t & 1) * BUF;
    char* nbuf = lds + ((t + 1) & 1) * BUF;
    const char* lA = buf;
    const char* lB = buf + BM * 128;
    const bool pf  = (t + 1 < nt);
    const int k0n  = (t + 1) << 6;

    // FRONT-LOAD all t+1 staging: full tile of latency cover
    if (pf) {
      if constexpr (A_F32) {
        load_A_f32(k0n);                       // f32 -> regs (compiler-tracked)
      } else {
        #pragma unroll
        for (int i = 0; i < RA; ++i) stage_A_round(nbuf, k0n, i);
      }
      #pragma unroll
      for (int i = 0; i < 4; ++i) stage_B_round(nbuf, k0n, i);
    }

    // B-frags once per tile, held in regs (compiler inserts lgkm waits)
    bf16x8 bfr[4][2];
    #pragma unroll
    for (int ni = 0; ni < 4; ++ni)
      #pragma unroll
      for (int h = 0; h < 2; ++h) {
        const int row = wn + ni * 16 + l15;
        const int sp  = (h * 4 + l4) ^ (row & 7);
        bfr[ni][h] = *(const bf16x8*)(lB + row * 128 + sp * 16);
      }

    #pragma unroll
    for (int q = 0; q < 4; ++q) {
      bf16x8 af[FPQ][2];
      #pragma unroll
      for (int f = 0; f < FPQ; ++f)
        #pragma unroll
        for (int h = 0; h < 2; ++h) {
          const int row = wm + (q * FPQ + f) * 16 + l15;
          const int sp  = (h * 4 + l4) ^ (row & 7);
          af[f][h] = *(const bf16x8*)(lA + row * 128 + sp * 16);
        }
      __builtin_amdgcn_s_setprio(1);
      #pragma unroll
      for (int f = 0; f < FPQ; ++f)
        #pragma unroll
        for (int ni = 0; ni < 4; ++ni)
          #pragma unroll
          for (int h = 0; h < 2; ++h)
            acc[q * FPQ + f][ni] = __builtin_amdgcn_mfma_f32_16x16x32_bf16(
                af[f][h], bfr[ni][h], acc[q * FPQ + f][ni], 0, 0, 0);
      __builtin_amdgcn_s_setprio(0);
    }

    if (A_F32 && pf) write_A_f32(nbuf);        // cvt+ds_write post-MFMA
    WAIT_VMCNT(0);                             // loads had a full tile to land
    if (A_F32) WAIT_LGKM0;                     // A ds_writes visible
    __builtin_amdgcn_s_barrier();              // tile boundary
  }

  // ---- epilogue: C/D layout col=lane&15, row=(lane>>4)*4+reg (m89) ---------
  #pragma unroll
  for (int ni = 0; ni < 4; ++ni) {
    const int n  = bn * BN + wn + ni * 16 + l15;
    const float bv = bias[n];
    #pragma unroll
    for (int mi = 0; mi < MI; ++mi) {
      #pragma unroll
      for (int r = 0; r < 4; ++r) {
        const int m  = bm * BM + wm + mi * 16 + l4 * 4 + r;
        const float t = acc[mi][ni][r] + bv;
        if (EPI == 0) {
          ((bf16_t*)out0)[(size_t)m * N + n] = __float2bfloat16(fmaxf(t, 0.f));
        } else {
          ((float*)out0)[(size_t)m * N + n] = rcp(1.f + ex2(-t * LOG2E));
        }
      }
    }
  }
}

// ---------------------------------------------------------------------------
// FUSED AB + stick-breaking + GEMM3 (R19/R21 structure: u prefetched to regs).
// ---------------------------------------------------------------------------
__global__ __launch_bounds__(512, 2)
void abstick_kernel(const bf16_t* __restrict__ A, const bf16_t* __restrict__ wabg,
                    const float* __restrict__ bab, const bf16_t* __restrict__ w2pg,
                    const float* __restrict__ b2, const float* __restrict__ u,
                    float* __restrict__ out_a, float* __restrict__ out_b,
                    bf16_t* __restrict__ h2)
{
  constexpr int BUF = 64 * 128 + 16384;        // 24576
  constexpr int PIL = 65536;
  constexpr int SMO = 73728;
  __shared__ char lds[100352];

  const int tid  = threadIdx.x;
  const int swzid = ((blockIdx.x & 7) * (gridDim.x >> 3)) + (blockIdx.x >> 3);
  const int bm   = swzid;
  const int wid  = tid >> 6;
  const int lane = tid & 63;
  const int l15  = lane & 15;
  const int l4   = lane >> 4;
  const int wm   = (wid >> 2) * 32;
  const int wn   = (wid & 3) * 32;
  const int uw   = __builtin_amdgcn_readfirstlane(wid);
  const int K    = HID;

  f32x4 acc[2][2] = {};

  auto stage_AB = [&](char* buf, int k0) {
    {
      const int c  = tid;
      const int r  = c >> 3;
      const int sp = c & 7;
      const int sl = sp ^ (r & 7);
      gload16(A + (size_t)(bm * 64 + r) * K + k0 + sl * 8, buf + uw * 1024);
    }
    char* lB = buf + 8192;
    #pragma unroll
    for (int i = 0; i < 2; ++i) {
      const int c  = (i * 8 + uw) * 64 + lane;
      const int r  = c >> 3;
      const int sp = c & 7;
      const int sl = sp ^ (r & 7);
      gload16(wabg + (size_t)r * K + k0 + sl * 8, lB + (i * 8 + uw) * 1024);
    }
  };
  auto compute1 = [&](const char* buf) {
    const char* lA = buf;
    const char* lB = buf + 8192;
    #pragma unroll
    for (int h = 0; h < 2; ++h) {
      bf16x8 af[2], bfr[2];
      #pragma unroll
      for (int mi = 0; mi < 2; ++mi) {
        const int row = wm + mi * 16 + l15;
        const int sp  = (h * 4 + l4) ^ (row & 7);
        af[mi] = *(const bf16x8*)(lA + row * 128 + sp * 16);
      }
      #pragma unroll
      for (int ni = 0; ni < 2; ++ni) {
        const int row = wn + ni * 16 + l15;
        const int sp  = (h * 4 + l4) ^ (row & 7);
        bfr[ni] = *(const bf16x8*)(lB + row * 128 + sp * 16);
      }
      #pragma unroll
      for (int mi = 0; mi < 2; ++mi)
        #pragma unroll
        for (int ni = 0; ni < 2; ++ni)
          acc[mi][ni] = __builtin_amdgcn_mfma_f32_16x16x32_bf16(
              af[mi], bfr[ni], acc[mi][ni], 0, 0, 0);
    }
  };

  stage_AB(lds, 0);
  stage_AB(lds + BUF, 64);
  for (int t = 0; t < 8; ++t) {
    if (t + 1 < 8) WAIT_VMCNT(3);
    else           WAIT_VMCNT(0);
    __builtin_amdgcn_s_barrier();
    compute1(lds + (t & 1) * BUF);
    __builtin_amdgcn_s_barrier();
    __builtin_amdgcn_sched_barrier(0);
    if (t + 2 < 8) stage_AB(lds + (t & 1) * BUF, (t + 2) << 6);
  }

  // PREFETCH u for this wave's 8 rows (issued together; latency covered by
  // w2p staging + epilogue + sm writes + barrier).
  const int ul = (lane < 49) ? lane : 0;
  float ureg[8];
  #pragma unroll
  for (int rr = 0; rr < 8; ++rr) {
    const size_t m = (size_t)(bm * 64 + wid * 8 + rr);
    ureg[rr] = u[m * 50 + ul];
  }

  // issue w2p staging (drains during phase 2)
  #pragma unroll
  for (int i = 0; i < 8; ++i) {
    const int c  = (i * 8 + uw) * 64 + lane;
    const int r  = c >> 3;
    const int sp = c & 7;
    const int sl = sp ^ (r & 7);
    gload16(w2pg + (size_t)r * 64 + sl * 8, lds + (i * 8 + uw) * 1024);
  }

  float* sm = (float*)(lds + SMO);             // [64][104]
  #pragma unroll
  for (int ni = 0; ni < 2; ++ni) {
    const int n  = wn + ni * 16 + l15;
    const float bv = bab[n];
    #pragma unroll
    for (int mi = 0; mi < 2; ++mi) {
      #pragma unroll
      for (int r = 0; r < 4; ++r) {
        const int ml = wm + mi * 16 + l4 * 4 + r;
        const int m  = bm * 64 + ml;
        const float t = acc[mi][ni][r] + bv;
        if (n < 100) {
          const float y =
              (t > 20.f ? t : lg2(1.f + ex2(t * LOG2E)) * RLOG2E) + 1e-4f;
          if (n < 50) out_a[(size_t)m * 50 + n] = y;
          else        out_b[(size_t)m * 50 + (n - 50)] = y;
          sm[ml * 104 + n + (n < 50 ? 0 : 2)] = y;
        }
      }
    }
  }
  __syncthreads();

  #pragma unroll 1
  for (int rr = 0; rr < 8; ++rr) {
    const int rl = wid * 8 + rr;
    const size_t m = (size_t)(bm * 64 + rl);
    float v = 1.f, t = 1.f;
    if (lane < 49) {
      const float a  = sm[rl * 104 + lane];
      const float b  = sm[rl * 104 + 52 + lane];
      const float uu = ureg[rr];
      const float tb = ex2(lg2(uu) * rcp(b));
      v = ex2(lg2(1.f - tb) * rcp(a));
      t = 1.f - v;
    }
    float p = t;
    #pragma unroll
    for (int d = 1; d < 64; d <<= 1) {
      const float o = __shfl_up(p, d, 64);
      if (lane >= d) p *= o;
    }
    float e = __shfl_up(p, 1, 64);
    if (lane == 0) e = 1.f;
    const float piv = (lane < 50) ? v * e : 0.f;
    *(unsigned short*)(lds + PIL + rl * 128 +
                       (((lane >> 3) ^ (rl & 7)) << 4) + ((lane & 7) << 1)) =
        f2b_u(piv);
  }
  __syncthreads();

  const int wn3 = (wid & 3) * 128;
  f32x4 acc3[2][8] = {};
  #pragma unroll
  for (int h = 0; h < 2; ++h) {
    bf16x8 af[2], bfr[8];
    #pragma unroll
    for (int mi = 0; mi < 2; ++mi) {
      const int row = wm + mi * 16 + l15;
      const int sp  = (h * 4 + l4) ^ (row & 7);
      af[mi] = *(const bf16x8*)(lds + PIL + row * 128 + sp * 16);
    }
    #pragma unroll
    for (int ni = 0; ni < 8; ++ni) {
      const int row = wn3 + ni * 16 + l15;
      const int sp  = (h * 4 + l4) ^ (row & 7);
      bfr[ni] = *(const bf16x8*)(lds + row * 128 + sp * 16);
    }
    #pragma unroll
    for (int mi = 0; mi < 2; ++mi)
      #pragma unroll
      for (int ni = 0; ni < 8; ++ni)
        acc3[mi][ni] = __builtin_amdgcn_mfma_f32_16x16x32_bf16(
            af[mi], bfr[ni], acc3[mi][ni], 0, 0, 0);
  }
  #pragma unroll
  for (int ni = 0; ni < 8; ++ni) {
    const int n  = wn3 + ni * 16 + l15;
    const float bv = b2[n];
    #pragma unroll
    for (int mi = 0; mi < 2; ++mi) {
      #pragma unroll
      for (int r = 0; r < 4; ++r) {
        const int m  = bm * 64 + wm + mi * 16 + l4 * 4 + r;
        h2[(size_t)m * HID + n] =
            __float2bfloat16(fmaxf(acc3[mi][ni][r] + bv, 0.f));
      }
    }
  }
}

// ---------------------------------------------------------------------------
extern "C" void kernel_launch(void* const* d_in, const int* in_sizes, int n_in,
                              void* d_out, int out_size, void* d_ws, size_t ws_size,
                              hipStream_t stream)
{
  const float* x  = (const float*)d_in[0];
  const float* u  = (const float*)d_in[1];
  const float* W1 = (const float*)d_in[2];
  const float* b1 = (const float*)d_in[3];
  const float* Wa = (const float*)d_in[4];
  const float* ba = (const float*)d_in[5];
  const float* Wb = (const float*)d_in[6];
  const float* bb = (const float*)d_in[7];
  const float* W2 = (const float*)d_in[8];
  const float* b2 = (const float*)d_in[9];
  const float* W3 = (const float*)d_in[10];
  const float* b3 = (const float*)d_in[11];

  float* recon  = (float*)d_out;
  float* oalpha = recon + (size_t)BATCH * NDIM;
  float* obeta  = oalpha + (size_t)BATCH * LAT;

  char* ws = (char*)d_ws;
  bf16_t* h2  = (bf16_t*)(ws);                 // 16,777,216
  bf16_t* h   = (bf16_t*)(ws + 16777216);      // 16,777,216
  bf16_t* w1  = (bf16_t*)(ws + 33554432);      //  1,048,576
  bf16_t* w3  = (bf16_t*)(ws + 34603008);      //  1,048,576
  bf16_t* wab = (bf16_t*)(ws + 35651584);      //    131,072
  bf16_t* w2p = (bf16_t*)(ws + 35782656);      //     65,536
  float*  bab = (float*)(ws + 35848192);       //        512

  prep_w_kernel<<<512, 256, 0, stream>>>(W1, W3, Wa, Wb, W2, ba, bb,
                                         w1, w3, wab, w2p, bab);
  // h = relu(x @ W1^T + b1); BM=128xBN=256, x raw f32 reg-staged, grid 256
  gemm256_kernel<1, 0, 128><<<256, 512, 0, stream>>>(
      x, w1, b1, (void*)h, BATCH, HID, NDIM);
  // alpha/beta -> d_out, fused stick + GEMM3 -> h2  (grid 256)
  abstick_kernel<<<256, 512, 0, stream>>>(
      h, wab, bab, w2p, b2, u, oalpha, obeta, h2);
  // recon = sigmoid(h2 @ W3^T + b3); BM=256xBN=256, grid 256 (no-spill LB)
  gemm256_kernel<0, 1, 256><<<256, 512, 0, stream>>>(
      h2, w3, b3, (void*)recon, BATCH, NDIM, HID);
}